// Round 12
// baseline (4315.762 us; speedup 1.0000x reference)
//
#include <hip/hip_runtime.h>

// LinearAttention, S=4096 B=8 D=1024.
// out = Q @ (K^T V')_b^T + bo, V' = x Wvo^T + bvo, Wvo = Wo Wv (folded).
// x permuted to [b][s][d]; fused K|V' proj -> KVb [b][2048][s]; split-K4 KVo.
// gemm_db: 256^2 tile, BK=32, 64KB double-buffered LDS -> 2 blocks/CU;
// 2-barrier K-loop, counted vmcnt(4) (stage t+2 during compute t).
// LDS epilogues sized for 64KB (bf16 4x64-row rounds / fp32 8x32-row rounds).

typedef __bf16 bf16;
typedef __attribute__((ext_vector_type(8))) __bf16 bf16x8;
typedef __attribute__((ext_vector_type(4))) __bf16 bf16x4;
typedef __attribute__((ext_vector_type(4))) float f32x4;

static constexpr int S = 4096;
static constexpr int B = 8;
static constexpr int D = 1024;
static constexpr int SB = S * B;
static constexpr long long NELEM = (long long)SB * D;

__device__ __forceinline__ void load_lds16(const bf16* g, void* l)
{
    __builtin_amdgcn_global_load_lds(
        (const __attribute__((address_space(1))) void*)g,
        (__attribute__((address_space(3))) void*)l, 16, 0, 0);
}

// ---------------- fp32 -> bf16 convert ----------------
__global__ void cvt_f32_to_bf16(const float* __restrict__ in, bf16* __restrict__ out, int n)
{
    int i = (blockIdx.x * blockDim.x + threadIdx.x) * 4;
    int stride = gridDim.x * blockDim.x * 4;
    for (; i < n; i += stride) {
        float4 v = *(const float4*)(in + i);
        bf16x4 o;
        o[0] = (bf16)v.x; o[1] = (bf16)v.y; o[2] = (bf16)v.z; o[3] = (bf16)v.w;
        *(bf16x4*)(out + i) = o;
    }
}

// ---------------- x [S][B][D] fp32 -> xbp [B][S][D] bf16 ----------------
__global__ void cvt_permute(const float* __restrict__ in, bf16* __restrict__ out)
{
    long long i = ((long long)blockIdx.x * blockDim.x + threadIdx.x) * 8;
    const long long stride = (long long)gridDim.x * blockDim.x * 8;
    for (; i < NELEM; i += stride) {
        const long long s = i >> 13;
        const long long r = i & 8191;
        const long long b = r >> 10;
        const long long d = r & 1023;
        float4 v0 = *(const float4*)(in + i);
        float4 v1 = *(const float4*)(in + i + 4);
        bf16x8 o;
        o[0] = (bf16)v0.x; o[1] = (bf16)v0.y; o[2] = (bf16)v0.z; o[3] = (bf16)v0.w;
        o[4] = (bf16)v1.x; o[5] = (bf16)v1.y; o[6] = (bf16)v1.z; o[7] = (bf16)v1.w;
        *(bf16x8*)(out + b * ((long long)S * D) + s * D + d) = o;
    }
}

// ---------------- Wv (fp32 [e][d]) -> WvT (bf16 [d][e]) ----------------
__global__ __launch_bounds__(256) void cvt_transpose_1024(
    const float* __restrict__ in, bf16* __restrict__ out)
{
    __shared__ bf16 tile[64][72];
    const int e0 = blockIdx.y * 64;
    const int d0 = blockIdx.x * 64;
    const int t  = threadIdx.x;
    const int rl = t >> 3;
    const int c8 = (t & 7) * 8;
    #pragma unroll
    for (int p = 0; p < 2; ++p) {
        int r = rl + p * 32;
        float4 v0 = *(const float4*)(in + (long long)(e0 + r) * D + d0 + c8);
        float4 v1 = *(const float4*)(in + (long long)(e0 + r) * D + d0 + c8 + 4);
        tile[c8+0][r] = (bf16)v0.x; tile[c8+1][r] = (bf16)v0.y;
        tile[c8+2][r] = (bf16)v0.z; tile[c8+3][r] = (bf16)v0.w;
        tile[c8+4][r] = (bf16)v1.x; tile[c8+5][r] = (bf16)v1.y;
        tile[c8+6][r] = (bf16)v1.z; tile[c8+7][r] = (bf16)v1.w;
    }
    __syncthreads();
    #pragma unroll
    for (int p = 0; p < 2; ++p) {
        int dr = rl + p * 32;
        *(bf16x8*)(out + (long long)(d0 + dr) * D + e0 + c8) = *(bf16x8*)(&tile[dr][c8]);
    }
}

// ---------------- bvo = Wo @ bv (fp32) ----------------
__global__ __launch_bounds__(256) void bvo_kernel(
    const float* __restrict__ Wo, const float* __restrict__ bv, float* __restrict__ bvo)
{
    const int row = blockIdx.x;
    const int t = threadIdx.x;
    float4 w = *(const float4*)(Wo + (long long)row * D + t * 4);
    float4 b = *(const float4*)(bv + t * 4);
    float s = w.x*b.x + w.y*b.y + w.z*b.z + w.w*b.w;
    __shared__ float red[256];
    red[t] = s; __syncthreads();
    for (int off = 128; off > 0; off >>= 1) {
        if (t < off) red[t] += red[t + off];
        __syncthreads();
    }
    if (t == 0) bvo[row] = red[0];
}

// ---------------- KVo = sum of 4 partials (bf16) ----------------
__global__ __launch_bounds__(256) void kv_add4(const bf16* __restrict__ p, bf16* __restrict__ o)
{
    const long long DD = (long long)D * D;
    const int b = blockIdx.y;
    const long long i = ((long long)blockIdx.x * 256 + threadIdx.x) * 8;
    float s[8] = {};
    #pragma unroll
    for (int h = 0; h < 4; ++h) {
        bf16x8 u = *(const bf16x8*)(p + (4 * b + h) * DD + i);
        #pragma unroll
        for (int j = 0; j < 8; ++j) s[j] += (float)u[j];
    }
    bf16x8 r;
    #pragma unroll
    for (int j = 0; j < 8; ++j) r[j] = (bf16)s[j];
    *(bf16x8*)(o + b * DD + i) = r;
}

// ---------------- R3 ring GEMM (small shapes: Wvo only) ----------------
template<int BM, int BN, int WM, int WN, int EPI, int OUTF32, int BIASROW>
__global__ __launch_bounds__(WM * WN * 64, 2) void gemm_bt(
    const bf16* __restrict__ A, const bf16* __restrict__ Bm,
    const float* __restrict__ bias, void* __restrict__ Cout,
    int lda, int ldb, int ldc, int K,
    long long aBatch, long long bBatch, long long cBatch)
{
    constexpr int THREADS = WM * WN * 64;
    constexpr int WROWS = BM / WM, WCOLS = BN / WN;
    constexpr int MI = WROWS / 16, NI = WCOLS / 16;
    constexpr int ABYTES = BM * 64;
    constexpr int BBYTES = BN * 64;
    constexpr int BUF = ABYTES + BBYTES;

    __shared__ unsigned char smem[4 * BUF];

    const int tid  = threadIdx.x;
    const int lane = tid & 63;
    const int wave = tid >> 6;
    const int wr   = wave / WN;
    const int wc   = wave % WN;
    const int bz   = blockIdx.z;

    const int nx  = gridDim.x;
    const int bid = blockIdx.y * nx + blockIdx.x;
    const int cpx = (nx * gridDim.y) >> 3;
    const int swz = (bid & 7) * cpx + (bid >> 3);
    const long long m0 = (long long)(swz / nx) * BM;
    const long long n0 = (long long)(swz % nx) * BN;

    const bf16* Ab = A  + bz * aBatch + m0 * lda;
    const bf16* Bb = Bm + bz * bBatch + n0 * ldb;

    f32x4 acc[MI][NI] = {};
    const int NT = K >> 5;

    auto stage = [&](int t) {
        unsigned char* dst = smem + (t & 3) * BUF;
        const long long kk = (long long)t << 5;
        #pragma unroll
        for (int j = 0; j < 2; ++j) {
            const int g  = wave * 64 + lane + j * THREADS;
            const int gs = g ^ ((g >> 3) & 3);
            const int row = gs >> 2, col = (gs & 3) * 8;
            load_lds16(Ab + (long long)row * lda + kk + col,
                       dst + (wave * 64 + j * THREADS) * 16);
        }
        #pragma unroll
        for (int j = 0; j < 2; ++j) {
            const int g  = wave * 64 + lane + j * THREADS;
            const int gs = g ^ ((g >> 3) & 3);
            const int row = gs >> 2, col = (gs & 3) * 8;
            load_lds16(Bb + (long long)row * ldb + kk + col,
                       dst + ABYTES + (wave * 64 + j * THREADS) * 16);
        }
    };

    stage(0); stage(1); stage(2);

    const int ko2 = (lane >> 4) * 16;
    const int la15 = lane & 15;

    for (int t = 0; t < NT; ++t) {
        if (t + 2 < NT)      asm volatile("s_waitcnt vmcnt(8)" ::: "memory");
        else if (t + 1 < NT) asm volatile("s_waitcnt vmcnt(4)" ::: "memory");
        else                 asm volatile("s_waitcnt vmcnt(0)" ::: "memory");
        __builtin_amdgcn_s_barrier();
        asm volatile("" ::: "memory");

        if (t + 3 < NT) stage(t + 3);

        const unsigned char* buf = smem + (t & 3) * BUF;
        bf16x8 a[MI], b[NI];
        #pragma unroll
        for (int mi = 0; mi < MI; ++mi) {
            int ad = (wr * WROWS + mi * 16 + la15) * 64 + ko2;
            ad ^= ((ad >> 7) & 3) << 4;
            a[mi] = *(const bf16x8*)(buf + ad);
        }
        #pragma unroll
        for (int ni = 0; ni < NI; ++ni) {
            int ad = (wc * WCOLS + ni * 16 + la15) * 64 + ko2;
            ad ^= ((ad >> 7) & 3) << 4;
            b[ni] = *(const bf16x8*)(buf + ABYTES + ad);
        }

        __builtin_amdgcn_s_setprio(1);
        #pragma unroll
        for (int mi = 0; mi < MI; ++mi)
            #pragma unroll
            for (int ni = 0; ni < NI; ++ni)
                acc[mi][ni] = __builtin_amdgcn_mfma_f32_16x16x32_bf16(
                    a[mi], b[ni], acc[mi][ni], 0, 0, 0);
        __builtin_amdgcn_s_setprio(0);
    }

    const int crow = (lane >> 4) * 4;
    const int ccol = lane & 15;
    #pragma unroll
    for (int ni = 0; ni < NI; ++ni) {
        const long long c = n0 + wc * WCOLS + ni * 16 + ccol;
        float bcol = 0.0f;
        if (!BIASROW && bias) bcol = bias[c];
        #pragma unroll
        for (int mi = 0; mi < MI; ++mi) {
            const long long r0 = m0 + wr * WROWS + mi * 16 + crow;
            #pragma unroll
            for (int j = 0; j < 4; ++j) {
                float v = acc[mi][ni][j];
                v += BIASROW ? bias[r0 + j] : bcol;
                if (EPI == 1) v = (v > 0.0f) ? (v + 1.0f) : __expf(v);
                const long long idx = bz * cBatch + (r0 + j) * ldc + c;
                if (OUTF32) ((float*)Cout)[idx] = v;
                else        ((bf16*)Cout)[idx]  = (bf16)v;
            }
        }
    }
}

// ---------------- 256^2 double-buffered GEMM, 2 blocks/CU ----------------
// BK=32, LDS = 2 x (A 16KB | B 16KB) = 64KB -> 2 blocks/CU.
// Per K-tile: {12 ds_read; lgkmcnt(0); barrier; stage(t+2)->buf[cur];
// 32 MFMA; vmcnt(4) [t+1 landed]; barrier}. Cross-block overlap hides drains.
// EPI: 1 = elu+1; 2 = elu+1 iff m0 < 1024. SPLITK: z = batch*SPLITK + kseg.
// GROUPN: 0 = row-major tile enum (A reuse); 1 = col-major (B reuse).
template<int EPI, int OUTF32, int BIASROW, int SPLITK, int GROUPN>
__global__ __launch_bounds__(512, 4) void gemm_db(
    const bf16* __restrict__ A, const bf16* __restrict__ Bm,
    const float* __restrict__ bias, void* __restrict__ Cout,
    int lda, int ldb, int ldc, int K,
    long long aBatch, long long bBatch, long long cBatch)
{
    __shared__ unsigned char smem[65536];

    const int tid  = threadIdx.x;
    const int lane = tid & 63;
    const int wave = tid >> 6;
    const int wr   = wave >> 2;        // 0..1
    const int wc   = wave & 3;         // 0..3
    const int bz    = blockIdx.z;
    const int batch = bz / SPLITK;
    const int kseg  = bz % SPLITK;

    const int nx  = gridDim.x;
    const int ny  = gridDim.y;
    const int bid = blockIdx.y * nx + blockIdx.x;
    const int cpx = (nx * ny) >> 3;
    const int swzb = (bid & 7) * cpx + (bid >> 3);
    long long m0, n0;
    if (GROUPN) { n0 = (long long)(swzb / ny) * 256; m0 = (long long)(swzb % ny) * 256; }
    else        { m0 = (long long)(swzb / nx) * 256; n0 = (long long)(swzb % nx) * 256; }

    const bf16* Ab = A  + batch * aBatch + m0 * lda + (long long)kseg * K;
    const bf16* Bb = Bm + batch * bBatch + n0 * ldb + (long long)kseg * K;

    // staging: row = wave*16 + (lane>>2) (+128 for 2nd issue), col granule
    // sg = (lane&3) ^ row-bits-1-2 (inverse T2 swizzle on the source)
    const int sg = (lane & 3) ^ ((lane >> 3) & 3);
    const long long srow = wave * 16 + (lane >> 2);
    const bf16* sA0 = Ab + srow * lda + sg * 8;
    const bf16* sA1 = sA0 + 128 * (long long)lda;
    const bf16* sB0 = Bb + srow * ldb + sg * 8;
    const bf16* sB1 = sB0 + 128 * (long long)ldb;
    const int dstoff = wave * 1024;

    // ds_read granule: (row)*4 + (kslot ^ row-bits-1-2), row = base + la15
    const int la15 = lane & 15;
    const int rsw  = (lane >> 4) ^ ((la15 >> 1) & 3);
    const int a16  = (wr * 128 + la15) * 4 + rsw;   // + mi*64
    const int b16  = (wc * 64  + la15) * 4 + rsw;   // + ni*64

    f32x4 acc[8][4] = {};
    const int NT = K >> 5;

    auto stage = [&](int T, int cur) {
        const long long kp = (long long)T << 5;
        unsigned char* base = smem + cur * 32768;
        load_lds16(sA0 + kp, base + dstoff);
        load_lds16(sA1 + kp, base + 8192 + dstoff);
        load_lds16(sB0 + kp, base + 16384 + dstoff);
        load_lds16(sB1 + kp, base + 24576 + dstoff);
    };

    stage(0, 0); stage(1, 1);
    asm volatile("s_waitcnt vmcnt(4)" ::: "memory");   // tile 0 landed
    __builtin_amdgcn_s_barrier();

    for (int t = 0; t < NT; ++t) {
        const int cur = t & 1;
        const unsigned char* Abase = smem + cur * 32768;
        const unsigned char* Bbase = Abase + 16384;

        bf16x8 afr[8], bfr[4];
        #pragma unroll
        for (int ni = 0; ni < 4; ++ni)
            bfr[ni] = *(const bf16x8*)(Bbase + (b16 + ni * 64) * 16);
        #pragma unroll
        for (int m = 0; m < 8; ++m)
            afr[m] = *(const bf16x8*)(Abase + (a16 + m * 64) * 16);

        asm volatile("s_waitcnt lgkmcnt(0)" ::: "memory");
        __builtin_amdgcn_s_barrier();          // all reads of buf[cur] done

        if (t + 2 < NT) stage(t + 2, cur);     // overwrite now race-free

        __builtin_amdgcn_s_setprio(1);
        #pragma unroll
        for (int m = 0; m < 8; ++m)
            #pragma unroll
            for (int ni = 0; ni < 4; ++ni)
                acc[m][ni] = __builtin_amdgcn_mfma_f32_16x16x32_bf16(
                    afr[m], bfr[ni], acc[m][ni], 0, 0, 0);
        __builtin_amdgcn_s_setprio(0);

        // certify tile t+1 (in-order retirement: keep t+2's 4 loads in flight)
        if (t + 2 < NT)      asm volatile("s_waitcnt vmcnt(4)" ::: "memory");
        else if (t + 1 < NT) asm volatile("s_waitcnt vmcnt(0)" ::: "memory");
        __builtin_amdgcn_s_barrier();
    }

    // ---- epilogue (64KB-budget LDS rounds) ----
    const bool doElu = (EPI == 1) || (EPI == 2 && m0 < 1024);
    const long long cb = (long long)bz * cBatch;
    const int crow = (lane >> 4) * 4;

    if constexpr (OUTF32 != 0) {
        // fp32: 8 rounds of 32-row chunks [32][260] f32 (33.3KB)
        float* lt = (float*)smem;
        #pragma unroll
        for (int q = 0; q < 8; ++q) {
            __builtin_amdgcn_s_barrier();
            if (wr == (q >> 2)) {
                #pragma unroll
                for (int f = 0; f < 2; ++f) {
                    const int mi = (q & 3) * 2 + f;
                    const int lrow = f * 16 + crow;            // 0..28
                    const long long r0 = m0 + q * 32 + lrow;
                    #pragma unroll
                    for (int ni = 0; ni < 4; ++ni) {
                        const int lcol = wc * 64 + ni * 16 + la15;
                        float bb = 0.0f;
                        if (!BIASROW && bias) bb = bias[n0 + lcol];
                        #pragma unroll
                        for (int j = 0; j < 4; ++j) {
                            float v = acc[mi][ni][j] + (BIASROW ? bias[r0 + j] : bb);
                            if (doElu) v = (v > 0.0f) ? (v + 1.0f) : __expf(v);
                            lt[(lrow + j) * 260 + lcol] = v;
                        }
                    }
                }
            }
            __builtin_amdgcn_s_barrier();
            #pragma unroll
            for (int it = 0; it < 4; ++it) {
                const int chk = it * 512 + tid;    // 0..2047
                const int r   = chk >> 6;          // 0..31
                const int g   = chk & 63;
                float4 v = *(const float4*)(lt + r * 260 + g * 4);
                *(float4*)((float*)Cout + cb + (m0 + q * 32 + r) * ldc + n0 + g * 4) = v;
            }
        }
    } else {
        // bf16: 4 rounds of 64-row chunks [64][264] bf16 (33.8KB)
        bf16* lt = (bf16*)smem;
        #pragma unroll
        for (int q = 0; q < 4; ++q) {
            __builtin_amdgcn_s_barrier();
            if (wr == (q >> 1)) {
                #pragma unroll
                for (int f = 0; f < 4; ++f) {
                    const int mi = (q & 1) * 4 + f;
                    const int lrow = f * 16 + crow;            // 0..60
                    const long long r0 = m0 + q * 64 + lrow;
                    #pragma unroll
                    for (int ni = 0; ni < 4; ++ni) {
                        const int lcol = wc * 64 + ni * 16 + la15;
                        float bb = 0.0f;
                        if (!BIASROW && bias) bb = bias[n0 + lcol];
                        #pragma unroll
                        for (int j = 0; j < 4; ++j) {
                            float v = acc[mi][ni][j] + (BIASROW ? bias[r0 + j] : bb);
                            if (doElu) v = (v > 0.0f) ? (v + 1.0f) : __expf(v);
                            lt[(lrow + j) * 264 + lcol] = (bf16)v;
                        }
                    }
                }
            }
            __builtin_amdgcn_s_barrier();
            #pragma unroll
            for (int it = 0; it < 4; ++it) {
                const int chk = it * 512 + tid;    // 0..2047
                const int m   = chk >> 5;          // 0..63
                const int nof = (chk & 31) * 8;
                bf16x8 v = *(const bf16x8*)(lt + m * 264 + nof);
                *(bf16x8*)((bf16*)Cout + cb + (m0 + q * 64 + m) * ldc + n0 + nof) = v;
            }
        }
    }
}

// ---------------- launch ----------------
extern "C" void kernel_launch(void* const* d_in, const int* in_sizes, int n_in,
                              void* d_out, int out_size, void* d_ws, size_t ws_size,
                              hipStream_t stream)
{
    const float* x  = (const float*)d_in[0];
    const float* Wq = (const float*)d_in[1];
    const float* bq = (const float*)d_in[2];
    const float* Wk = (const float*)d_in[3];
    const float* bk = (const float*)d_in[4];
    const float* Wv = (const float*)d_in[5];
    const float* bv = (const float*)d_in[6];
    const float* Wo = (const float*)d_in[7];
    const float* bo = (const float*)d_in[8];
    float* out = (float*)d_out;

    // ws layout (152 MiB):
    //  [0,64M)    xbp [b][s][d]
    //  [64M,128M) KVo partials (4x2MB x 8 = 64MB) -> then Qb (partials dead)
    //  [128M,144M) wvT(2MB)+bkvo(8KB) temps -> then KVo (16MB; temps dead)
    //  [144M,152M) wqb(2MB) wob(2MB) wkvo(4MB = [Wk;Wvo] 2048x1024)
    char* ws = (char*)d_ws;
    if (ws_size < (size_t)159383552) return;
    bf16*  xbp  = (bf16*)(ws + 0);
    bf16*  part = (bf16*)(ws + 67108864);
    bf16*  Qb   = (bf16*)(ws + 67108864);
    bf16*  wvT  = (bf16*)(ws + 134217728);
    float* bkvo = (float*)(ws + 134217728 + 2097152);
    bf16*  KVo  = (bf16*)(ws + 134217728);
    bf16*  wqb  = (bf16*)(ws + 150994944);
    bf16*  wob  = wqb + 1048576;
    bf16*  wkvo = wob + 1048576;           // [2048][1024]: rows 0-1023 Wk, 1024-2047 Wvo
    bf16*  KVb  = (bf16*)d_out;            // [b][2048][S]: rows 0-1023 Kt, 1024-2047 Vt'

    const long long SD = (long long)S * D;

    // 1) converts + folded-weight prep
    cvt_permute<<<8192, 256, 0, stream>>>(x, xbp);
    cvt_f32_to_bf16<<<1024, 256, 0, stream>>>(Wq, wqb, D * D);
    cvt_f32_to_bf16<<<1024, 256, 0, stream>>>(Wo, wob, D * D);
    cvt_f32_to_bf16<<<1024, 256, 0, stream>>>(Wk, wkvo, D * D);
    cvt_transpose_1024<<<dim3(16, 16), 256, 0, stream>>>(Wv, wvT);
    bvo_kernel<<<1024, 256, 0, stream>>>(Wo, bv, bkvo + 1024);
    hipMemcpyAsync(bkvo, bk, D * sizeof(float), hipMemcpyDeviceToDevice, stream);

    // 2) Wvo rows: wkvo[1024+e'][d] = sum_e Wo[e'][e] Wv[e][d]
    gemm_bt<128, 128, 2, 2, 0, 0, 0><<<dim3(8, 8, 1), 256, 0, stream>>>(
        wob, wvT, nullptr, wkvo + (long long)1024 * 1024, D, D, D, D, 0, 0, 0);

    // 3) fused K|V' projection: KVb[b][r][s] = [Wk;Wvo] @ xbp_b^T, elu+1 for r<1024
    gemm_db<2, 0, 1, 1, 1><<<dim3(16, 8, 8), 512, 0, stream>>>(
        wkvo, xbp, bkvo, KVb, D, D, S, D,
        0, SD, (long long)2048 * S);

    // 4) KVo partials: part[4b+h][e'][d] = sum_{s in quarter h} Vt' Kt
    gemm_db<0, 0, 0, 4, 0><<<dim3(4, 4, 32), 512, 0, stream>>>(
        KVb + (long long)1024 * S, KVb, nullptr, part, S, S, D, 1024,
        (long long)2048 * S, (long long)2048 * S, (long long)D * D);

    // 5) KVo = sum of 4 partials
    kv_add4<<<dim3(512, 8), 256, 0, stream>>>(part, KVo);

    // 6) Qb[b][s][d] = elu(xbp_b Wq^T + bq)+1  (overwrites partials — dead)
    gemm_db<1, 0, 0, 1, 0><<<dim3(4, 16, 8), 512, 0, stream>>>(
        xbp, wqb, bq, Qb, D, D, D, D, SD, 0, SD);

    // 7) out[s][b][e'] = Qb[b] @ KVo[b]^T + bo  (fp32; C row s at b*D offset)
    gemm_db<0, 1, 0, 1, 0><<<dim3(4, 16, 8), 512, 0, stream>>>(
        Qb, KVo, bo, out, D, D, B * D, D,
        SD, (long long)D * D, (long long)D);
}

// Round 13
// 517.178 us; speedup vs baseline: 8.3448x; 8.3448x over previous
//
#include <hip/hip_runtime.h>

// LinearAttention, S=4096 B=8 D=1024.
// out = Q @ (K^T V')_b^T + bo, V' = x Wvo^T + bvo, Wvo = Wo Wv (folded).
// x permuted to [b][s][d]; fused K|V' proj -> KVb [b][2048][s]; split-K2 KVo.
// gemm_r128: 128^2 tile, BK=32, 32KB dbuf LDS -> 3 blocks/CU (m97 lineage).
// gemm8p (R11): 256^2, 8-phase, 1 barrier/phase — used for KVo split-K.
// LDS epilogues everywhere (bf16 512B/256B runs; fp32 float4 runs).

typedef __bf16 bf16;
typedef __attribute__((ext_vector_type(8))) __bf16 bf16x8;
typedef __attribute__((ext_vector_type(4))) __bf16 bf16x4;
typedef __attribute__((ext_vector_type(4))) float f32x4;

static constexpr int S = 4096;
static constexpr int B = 8;
static constexpr int D = 1024;
static constexpr int SB = S * B;
static constexpr long long NELEM = (long long)SB * D;

__device__ __forceinline__ void load_lds16(const bf16* g, void* l)
{
    __builtin_amdgcn_global_load_lds(
        (const __attribute__((address_space(1))) void*)g,
        (__attribute__((address_space(3))) void*)l, 16, 0, 0);
}

// ---------------- fp32 -> bf16 convert ----------------
__global__ void cvt_f32_to_bf16(const float* __restrict__ in, bf16* __restrict__ out, int n)
{
    int i = (blockIdx.x * blockDim.x + threadIdx.x) * 4;
    int stride = gridDim.x * blockDim.x * 4;
    for (; i < n; i += stride) {
        float4 v = *(const float4*)(in + i);
        bf16x4 o;
        o[0] = (bf16)v.x; o[1] = (bf16)v.y; o[2] = (bf16)v.z; o[3] = (bf16)v.w;
        *(bf16x4*)(out + i) = o;
    }
}

// ---------------- x [S][B][D] fp32 -> xbp [B][S][D] bf16 ----------------
__global__ void cvt_permute(const float* __restrict__ in, bf16* __restrict__ out)
{
    long long i = ((long long)blockIdx.x * blockDim.x + threadIdx.x) * 8;
    const long long stride = (long long)gridDim.x * blockDim.x * 8;
    for (; i < NELEM; i += stride) {
        const long long s = i >> 13;
        const long long r = i & 8191;
        const long long b = r >> 10;
        const long long d = r & 1023;
        float4 v0 = *(const float4*)(in + i);
        float4 v1 = *(const float4*)(in + i + 4);
        bf16x8 o;
        o[0] = (bf16)v0.x; o[1] = (bf16)v0.y; o[2] = (bf16)v0.z; o[3] = (bf16)v0.w;
        o[4] = (bf16)v1.x; o[5] = (bf16)v1.y; o[6] = (bf16)v1.z; o[7] = (bf16)v1.w;
        *(bf16x8*)(out + b * ((long long)S * D) + s * D + d) = o;
    }
}

// ---------------- Wv (fp32 [e][d]) -> WvT (bf16 [d][e]) ----------------
__global__ __launch_bounds__(256) void cvt_transpose_1024(
    const float* __restrict__ in, bf16* __restrict__ out)
{
    __shared__ bf16 tile[64][72];
    const int e0 = blockIdx.y * 64;
    const int d0 = blockIdx.x * 64;
    const int t  = threadIdx.x;
    const int rl = t >> 3;
    const int c8 = (t & 7) * 8;
    #pragma unroll
    for (int p = 0; p < 2; ++p) {
        int r = rl + p * 32;
        float4 v0 = *(const float4*)(in + (long long)(e0 + r) * D + d0 + c8);
        float4 v1 = *(const float4*)(in + (long long)(e0 + r) * D + d0 + c8 + 4);
        tile[c8+0][r] = (bf16)v0.x; tile[c8+1][r] = (bf16)v0.y;
        tile[c8+2][r] = (bf16)v0.z; tile[c8+3][r] = (bf16)v0.w;
        tile[c8+4][r] = (bf16)v1.x; tile[c8+5][r] = (bf16)v1.y;
        tile[c8+6][r] = (bf16)v1.z; tile[c8+7][r] = (bf16)v1.w;
    }
    __syncthreads();
    #pragma unroll
    for (int p = 0; p < 2; ++p) {
        int dr = rl + p * 32;
        *(bf16x8*)(out + (long long)(d0 + dr) * D + e0 + c8) = *(bf16x8*)(&tile[dr][c8]);
    }
}

// ---------------- bvo = Wo @ bv (fp32) ----------------
__global__ __launch_bounds__(256) void bvo_kernel(
    const float* __restrict__ Wo, const float* __restrict__ bv, float* __restrict__ bvo)
{
    const int row = blockIdx.x;
    const int t = threadIdx.x;
    float4 w = *(const float4*)(Wo + (long long)row * D + t * 4);
    float4 b = *(const float4*)(bv + t * 4);
    float s = w.x*b.x + w.y*b.y + w.z*b.z + w.w*b.w;
    __shared__ float red[256];
    red[t] = s; __syncthreads();
    for (int off = 128; off > 0; off >>= 1) {
        if (t < off) red[t] += red[t + off];
        __syncthreads();
    }
    if (t == 0) bvo[row] = red[0];
}

// ---------------- KVo = part0 + part1 (bf16) ----------------
__global__ __launch_bounds__(256) void kv_add(const bf16* __restrict__ p, bf16* __restrict__ o)
{
    const long long DD = (long long)D * D;
    const int b = blockIdx.y;
    const long long i = ((long long)blockIdx.x * 256 + threadIdx.x) * 8;
    bf16x8 u = *(const bf16x8*)(p + (2 * b) * DD + i);
    bf16x8 v = *(const bf16x8*)(p + (2 * b + 1) * DD + i);
    bf16x8 r;
    #pragma unroll
    for (int j = 0; j < 8; ++j) r[j] = (bf16)((float)u[j] + (float)v[j]);
    *(bf16x8*)(o + b * DD + i) = r;
}

// ---------------- R3 ring GEMM (small shapes: Wvo only) ----------------
template<int BM, int BN, int WM, int WN, int EPI, int OUTF32, int BIASROW>
__global__ __launch_bounds__(WM * WN * 64, 2) void gemm_bt(
    const bf16* __restrict__ A, const bf16* __restrict__ Bm,
    const float* __restrict__ bias, void* __restrict__ Cout,
    int lda, int ldb, int ldc, int K,
    long long aBatch, long long bBatch, long long cBatch)
{
    constexpr int THREADS = WM * WN * 64;
    constexpr int WROWS = BM / WM, WCOLS = BN / WN;
    constexpr int MI = WROWS / 16, NI = WCOLS / 16;
    constexpr int ABYTES = BM * 64;
    constexpr int BBYTES = BN * 64;
    constexpr int BUF = ABYTES + BBYTES;

    __shared__ unsigned char smem[4 * BUF];

    const int tid  = threadIdx.x;
    const int lane = tid & 63;
    const int wave = tid >> 6;
    const int wr   = wave / WN;
    const int wc   = wave % WN;
    const int bz   = blockIdx.z;

    const int nx  = gridDim.x;
    const int bid = blockIdx.y * nx + blockIdx.x;
    const int cpx = (nx * gridDim.y) >> 3;
    const int swz = (bid & 7) * cpx + (bid >> 3);
    const long long m0 = (long long)(swz / nx) * BM;
    const long long n0 = (long long)(swz % nx) * BN;

    const bf16* Ab = A  + bz * aBatch + m0 * lda;
    const bf16* Bb = Bm + bz * bBatch + n0 * ldb;

    f32x4 acc[MI][NI] = {};
    const int NT = K >> 5;

    auto stage = [&](int t) {
        unsigned char* dst = smem + (t & 3) * BUF;
        const long long kk = (long long)t << 5;
        #pragma unroll
        for (int j = 0; j < 2; ++j) {
            const int g  = wave * 64 + lane + j * THREADS;
            const int gs = g ^ ((g >> 3) & 3);
            const int row = gs >> 2, col = (gs & 3) * 8;
            load_lds16(Ab + (long long)row * lda + kk + col,
                       dst + (wave * 64 + j * THREADS) * 16);
        }
        #pragma unroll
        for (int j = 0; j < 2; ++j) {
            const int g  = wave * 64 + lane + j * THREADS;
            const int gs = g ^ ((g >> 3) & 3);
            const int row = gs >> 2, col = (gs & 3) * 8;
            load_lds16(Bb + (long long)row * ldb + kk + col,
                       dst + ABYTES + (wave * 64 + j * THREADS) * 16);
        }
    };

    stage(0); stage(1); stage(2);

    const int ko2 = (lane >> 4) * 16;
    const int la15 = lane & 15;

    for (int t = 0; t < NT; ++t) {
        if (t + 2 < NT)      asm volatile("s_waitcnt vmcnt(8)" ::: "memory");
        else if (t + 1 < NT) asm volatile("s_waitcnt vmcnt(4)" ::: "memory");
        else                 asm volatile("s_waitcnt vmcnt(0)" ::: "memory");
        __builtin_amdgcn_s_barrier();
        asm volatile("" ::: "memory");

        if (t + 3 < NT) stage(t + 3);

        const unsigned char* buf = smem + (t & 3) * BUF;
        bf16x8 a[MI], b[NI];
        #pragma unroll
        for (int mi = 0; mi < MI; ++mi) {
            int ad = (wr * WROWS + mi * 16 + la15) * 64 + ko2;
            ad ^= ((ad >> 7) & 3) << 4;
            a[mi] = *(const bf16x8*)(buf + ad);
        }
        #pragma unroll
        for (int ni = 0; ni < NI; ++ni) {
            int ad = (wc * WCOLS + ni * 16 + la15) * 64 + ko2;
            ad ^= ((ad >> 7) & 3) << 4;
            b[ni] = *(const bf16x8*)(buf + ABYTES + ad);
        }

        __builtin_amdgcn_s_setprio(1);
        #pragma unroll
        for (int mi = 0; mi < MI; ++mi)
            #pragma unroll
            for (int ni = 0; ni < NI; ++ni)
                acc[mi][ni] = __builtin_amdgcn_mfma_f32_16x16x32_bf16(
                    a[mi], b[ni], acc[mi][ni], 0, 0, 0);
        __builtin_amdgcn_s_setprio(0);
    }

    const int crow = (lane >> 4) * 4;
    const int ccol = lane & 15;
    #pragma unroll
    for (int ni = 0; ni < NI; ++ni) {
        const long long c = n0 + wc * WCOLS + ni * 16 + ccol;
        float bcol = 0.0f;
        if (!BIASROW && bias) bcol = bias[c];
        #pragma unroll
        for (int mi = 0; mi < MI; ++mi) {
            const long long r0 = m0 + wr * WROWS + mi * 16 + crow;
            #pragma unroll
            for (int j = 0; j < 4; ++j) {
                float v = acc[mi][ni][j];
                v += BIASROW ? bias[r0 + j] : bcol;
                if (EPI == 1) v = (v > 0.0f) ? (v + 1.0f) : __expf(v);
                const long long idx = bz * cBatch + (r0 + j) * ldc + c;
                if (OUTF32) ((float*)Cout)[idx] = v;
                else        ((bf16*)Cout)[idx]  = (bf16)v;
            }
        }
    }
}

// ---------------- 256^2 8-phase GEMM (R11, 1 barrier/phase) — KVo ----------------
template<int EPI, int OUTF32, int BIASROW, int SPLITK, int GROUPN>
__global__ __launch_bounds__(512, 1) void gemm8p(
    const bf16* __restrict__ A, const bf16* __restrict__ Bm,
    const float* __restrict__ bias, void* __restrict__ Cout,
    int lda, int ldb, int ldc, int K,
    long long aBatch, long long bBatch, long long cBatch)
{
    __shared__ unsigned char smem[131072];

    const int tid  = threadIdx.x;
    const int lane = tid & 63;
    const int wave = tid >> 6;
    const int wr   = wave >> 2;
    const int wc   = wave & 3;
    const int bz    = blockIdx.z;
    const int batch = bz / SPLITK;
    const int kseg  = bz % SPLITK;

    const int nx  = gridDim.x;
    const int ny  = gridDim.y;
    const int bid = blockIdx.y * nx + blockIdx.x;
    const int cpx = (nx * ny) >> 3;
    const int swzb = (bid & 7) * cpx + (bid >> 3);
    long long m0, n0;
    if (GROUPN) { n0 = (long long)(swzb / ny) * 256; m0 = (long long)(swzb % ny) * 256; }
    else        { m0 = (long long)(swzb / nx) * 256; n0 = (long long)(swzb % nx) * 256; }

    const bf16* Ab = A  + batch * aBatch + m0 * lda + (long long)kseg * K;
    const bf16* Bb = Bm + batch * bBatch + n0 * ldb + (long long)kseg * K;

    const int sg = (lane & 3) ^ ((lane >> 3) & 3);
    const long long srow = wave * 32 + (lane >> 2);
    const bf16* srcA  = Ab + srow * lda + sg * 8;
    const bf16* srcA2 = srcA + 16 * (long long)lda;
    const bf16* srcB  = Bb + srow * ldb + sg * 8;
    const bf16* srcB2 = srcB + 16 * (long long)ldb;
    const int dstoff = wave * 2048;

    const int la15 = lane & 15;
    const int rsw  = (lane >> 4) ^ ((la15 >> 1) & 3);
    const int a16  = (wr * 128 + la15) * 4 + rsw;
    const int b16  = (wc * 64  + la15) * 4 + rsw;

    f32x4 acc[8][4] = {};
    const int NT = K >> 6;
    const int NI = NT >> 1;

    auto stageA = [&](int T, int kh) {
        const int reg = ((((T & 1) << 1) | kh) << 14);
        const long long kp = ((long long)T << 6) + (kh << 5);
        load_lds16(srcA  + kp, smem + reg + dstoff);
        load_lds16(srcA2 + kp, smem + reg + dstoff + 1024);
    };
    auto stageB = [&](int T, int kh) {
        const int reg = 65536 + ((((T & 1) << 1) | kh) << 14);
        const long long kp = ((long long)T << 6) + (kh << 5);
        load_lds16(srcB  + kp, smem + reg + dstoff);
        load_lds16(srcB2 + kp, smem + reg + dstoff + 1024);
    };

    stageB(0, 0); stageA(0, 0); stageB(0, 1); stageA(0, 1);
    stageB(1, 0); stageA(1, 0); stageB(1, 1);
    asm volatile("s_waitcnt vmcnt(6)" ::: "memory");

    bf16x8 bfr[4];
    for (int i = 0; i < NI; ++i) {
        const int t = 2 * i;
        const bool nl = (i + 1 < NI);
        #pragma unroll
        for (int p = 0; p < 8; ++p) {
            const int ks  = (p >> 1) & 1;
            const int ch  = p & 1;
            const int buf = p >> 2;
            const int regA = ((buf << 1) | ks) << 14;
            const int regB = 65536 + regA;

            __builtin_amdgcn_s_barrier();
            __builtin_amdgcn_sched_barrier(0);

            bf16x8 afr[4];
            if (ch == 0) {
                #pragma unroll
                for (int ni = 0; ni < 4; ++ni)
                    bfr[ni] = *(const bf16x8*)(smem + regB + (b16 + ni * 64) * 16);
            }
            #pragma unroll
            for (int m4 = 0; m4 < 4; ++m4)
                afr[m4] = *(const bf16x8*)(smem + regA + (a16 + (ch * 4 + m4) * 64) * 16);

            if      (p == 0) stageA(t + 1, 1);
            else if (p == 1) { if (t + 2 < NT) stageB(t + 2, 0); }
            else if (p == 2) { if (t + 2 < NT) stageA(t + 2, 0); }
            else if (p == 3) { if (t + 2 < NT) stageB(t + 2, 1); }
            else if (p == 4) { if (t + 2 < NT) stageA(t + 2, 1); }
            else if (p == 5) { if (t + 3 < NT) stageB(t + 3, 0); }
            else if (p == 6) { if (t + 3 < NT) stageA(t + 3, 0); }
            else             { if (t + 3 < NT) stageB(t + 3, 1); }

            if (p == 3) {
                if (nl) asm volatile("s_waitcnt vmcnt(6)" ::: "memory");
                else    asm volatile("s_waitcnt vmcnt(0)" ::: "memory");
            } else if (p == 7) {
                if (nl) asm volatile("s_waitcnt vmcnt(6)" ::: "memory");
            }

            __builtin_amdgcn_s_setprio(1);
            #pragma unroll
            for (int m4 = 0; m4 < 4; ++m4)
                #pragma unroll
                for (int ni = 0; ni < 4; ++ni)
                    acc[ch * 4 + m4][ni] = __builtin_amdgcn_mfma_f32_16x16x32_bf16(
                        afr[m4], bfr[ni], acc[ch * 4 + m4][ni], 0, 0, 0);
            __builtin_amdgcn_s_setprio(0);
        }
    }

    const bool doElu = (EPI == 1) || (EPI == 2 && m0 < 1024);
    const long long cb = (long long)bz * cBatch;
    const int crow = (lane >> 4) * 4;

    if constexpr (OUTF32 != 0) {
        float* lt = (float*)smem;
        #pragma unroll
        for (int q = 0; q < 4; ++q) {
            __builtin_amdgcn_s_barrier();
            __builtin_amdgcn_sched_barrier(0);
            if (wr == (q >> 1)) {
                #pragma unroll
                for (int m4 = 0; m4 < 4; ++m4) {
                    const int mi = (q & 1) * 4 + m4;
                    const int lrow = m4 * 16 + crow;
                    const long long r0 = m0 + q * 64 + lrow;
                    #pragma unroll
                    for (int ni = 0; ni < 4; ++ni) {
                        const int lcol = wc * 64 + ni * 16 + la15;
                        float bb = 0.0f;
                        if (!BIASROW && bias) bb = bias[n0 + lcol];
                        #pragma unroll
                        for (int j = 0; j < 4; ++j) {
                            float v = acc[mi][ni][j] + (BIASROW ? bias[r0 + j] : bb);
                            if (doElu) v = (v > 0.0f) ? (v + 1.0f) : __expf(v);
                            lt[(lrow + j) * 260 + lcol] = v;
                        }
                    }
                }
            }
            __builtin_amdgcn_s_barrier();
            #pragma unroll
            for (int it = 0; it < 8; ++it) {
                const int chk = it * 512 + tid;
                const int r   = chk >> 6;
                const int g   = chk & 63;
                float4 v = *(const float4*)(lt + r * 260 + g * 4);
                *(float4*)((float*)Cout + cb + (m0 + q * 64 + r) * ldc + n0 + g * 4) = v;
            }
        }
    } else {
        bf16* lt = (bf16*)smem;
        #pragma unroll
        for (int half = 0; half < 2; ++half) {
            __builtin_amdgcn_s_barrier();
            __builtin_amdgcn_sched_barrier(0);
            if (wr == half) {
                #pragma unroll
                for (int mi = 0; mi < 8; ++mi) {
                    const int lrow = mi * 16 + crow;
                    const long long r0 = m0 + half * 128 + lrow;
                    #pragma unroll
                    for (int ni = 0; ni < 4; ++ni) {
                        const int lcol = wc * 64 + ni * 16 + la15;
                        float bb = 0.0f;
                        if (!BIASROW && bias) bb = bias[n0 + lcol];
                        #pragma unroll
                        for (int j = 0; j < 4; ++j) {
                            float v = acc[mi][ni][j] + (BIASROW ? bias[r0 + j] : bb);
                            if (doElu) v = (v > 0.0f) ? (v + 1.0f) : __expf(v);
                            lt[(lrow + j) * 264 + lcol] = (bf16)v;
                        }
                    }
                }
            }
            __builtin_amdgcn_s_barrier();
            #pragma unroll
            for (int it = 0; it < 8; ++it) {
                const int chk = it * 512 + tid;
                const int m   = chk >> 5;
                const int nof = (chk & 31) * 8;
                bf16x8 v = *(const bf16x8*)(lt + m * 264 + nof);
                *(bf16x8*)((bf16*)Cout + cb + (m0 + half * 128 + m) * ldc + n0 + nof) = v;
            }
        }
    }
}

// ---------------- 128^2 double-buffered GEMM, 3 blocks/CU ----------------
// 256 thr = 4 waves (2x2), per-wave 64x64 (acc 4x4 f32x4 = 64 VGPR).
// BK=32; LDS = 2 x (A 8KB | B 8KB) = 32 KB -> 3 blocks/CU (VGPR-permitting).
// K-tile: {8 ds_read b128 (contiguous 1KB/wave, conflict-free); lgkm(0)+bar;
// stage(t+2)->buf[cur]; 16 MFMA; vmcnt(4) [t+1 ready]; bar}.
// Granule swizzle: slot g holds (row=g>>2, ks=(g&3)^(row&3)).
// EPI: 1 = elu+1; 2 = elu+1 iff m0 < 1024. GROUPN: XCD reuse axis.
template<int EPI, int OUTF32, int BIASROW, int GROUPN>
__global__ __launch_bounds__(256, 2) void gemm_r128(
    const bf16* __restrict__ A, const bf16* __restrict__ Bm,
    const float* __restrict__ bias, void* __restrict__ Cout,
    int lda, int ldb, int ldc, int K,
    long long aBatch, long long bBatch, long long cBatch)
{
    __shared__ unsigned char smem[32768];

    const int tid  = threadIdx.x;
    const int lane = tid & 63;
    const int wave = tid >> 6;         // 0..3
    const int wr   = wave >> 1;        // 0..1
    const int wc   = wave & 1;         // 0..1
    const int bz   = blockIdx.z;

    const int nx  = gridDim.x;
    const int ny  = gridDim.y;
    const int bid = blockIdx.y * nx + blockIdx.x;
    const int cpx = (nx * ny) >> 3;
    const int swzb = (bid & 7) * cpx + (bid >> 3);
    long long m0, n0;
    if (GROUPN) { n0 = (long long)(swzb / ny) * 128; m0 = (long long)(swzb % ny) * 128; }
    else        { m0 = (long long)(swzb / nx) * 128; n0 = (long long)(swzb % nx) * 128; }

    const bf16* Ab = A  + bz * aBatch + m0 * lda;
    const bf16* Bb = Bm + bz * bBatch + n0 * ldb;

    // stage: thread stages granules g = tid + j*256 (j=0,1) for A and B.
    // slot g holds (row=g>>2, ks=(g&3)^(row&3)); LDS byte = g*16 (linear).
    const int g0row = tid >> 2;
    const int g0ks  = (tid & 3) ^ (g0row & 3);
    const int g1row = (tid + 256) >> 2;
    const int g1ks  = (tid & 3) ^ (g1row & 3);
    const bf16* sA0 = Ab + (long long)g0row * lda + g0ks * 8;
    const bf16* sA1 = Ab + (long long)g1row * lda + g1ks * 8;
    const bf16* sB0 = Bb + (long long)g0row * ldb + g0ks * 8;
    const bf16* sB1 = Bb + (long long)g1row * ldb + g1ks * 8;
    const int dst0 = tid * 16;         // = wave-uniform + lane*16

    auto stage = [&](int T, int cur) {
        const long long kp = (long long)T << 5;
        unsigned char* base = smem + cur * 16384;
        load_lds16(sA0 + kp, base + dst0);
        load_lds16(sA1 + kp, base + 4096 + dst0);
        load_lds16(sB0 + kp, base + 8192 + dst0);
        load_lds16(sB1 + kp, base + 8192 + 4096 + dst0);
    };

    // ds_read granule: row = base + la15 (base%4==0): g = row*4 + (hi^(la15&3))
    const int la15 = lane & 15;
    const int hi   = lane >> 4;
    const int gsw  = hi ^ (la15 & 3);
    const int abase = (wr * 64 + la15) * 4 + gsw;   // + mi*64
    const int bbase = (wc * 64 + la15) * 4 + gsw;   // + ni*64

    f32x4 acc[4][4] = {};
    const int NT = K >> 5;

    stage(0, 0); stage(1, 1);
    asm volatile("s_waitcnt vmcnt(4)" ::: "memory");   // tile 0 landed
    __builtin_amdgcn_s_barrier();

    for (int t = 0; t < NT; ++t) {
        const int cur = t & 1;
        const unsigned char* Abase = smem + cur * 16384;
        const unsigned char* Bbase = Abase + 8192;

        bf16x8 a[4], b[4];
        #pragma unroll
        for (int ni = 0; ni < 4; ++ni)
            b[ni] = *(const bf16x8*)(Bbase + (bbase + ni * 64) * 16);
        #pragma unroll
        for (int mi = 0; mi < 4; ++mi)
            a[mi] = *(const bf16x8*)(Abase + (abase + mi * 64) * 16);

        asm volatile("s_waitcnt lgkmcnt(0)" ::: "memory");
        __builtin_amdgcn_s_barrier();            // all reads of buf[cur] done

        if (t + 2 < NT) stage(t + 2, cur);       // overwrite now race-free

        __builtin_amdgcn_s_setprio(1);
        #pragma unroll
        for (int mi = 0; mi < 4; ++mi)
            #pragma unroll
            for (int ni = 0; ni < 4; ++ni)
                acc[mi][ni] = __builtin_amdgcn_mfma_f32_16x16x32_bf16(
                    a[mi], b[ni], acc[mi][ni], 0, 0, 0);
        __builtin_amdgcn_s_setprio(0);

        if (t + 2 < NT)      asm volatile("s_waitcnt vmcnt(4)" ::: "memory");
        else if (t + 1 < NT) asm volatile("s_waitcnt vmcnt(0)" ::: "memory");
        __builtin_amdgcn_s_barrier();
    }

    // ---- epilogue (32KB-budget LDS rounds) ----
    const bool doElu = (EPI == 1) || (EPI == 2 && m0 < 1024);
    const long long cb = (long long)bz * cBatch;
    const int crow = hi * 4;

    if constexpr (OUTF32 != 0) {
        // fp32: 4 rounds of 32-row chunks [32][132] f32 (16.9KB)
        float* lt = (float*)smem;
        #pragma unroll
        for (int q = 0; q < 4; ++q) {
            __builtin_amdgcn_s_barrier();
            if (wr == (q >> 1)) {
                #pragma unroll
                for (int f = 0; f < 2; ++f) {
                    const int mi = (q & 1) * 2 + f;
                    const int lrow = f * 16 + crow;            // 0..28
                    const long long r0 = m0 + q * 32 + lrow;
                    #pragma unroll
                    for (int ni = 0; ni < 4; ++ni) {
                        const int lcol = wc * 64 + ni * 16 + la15;
                        float bb = 0.0f;
                        if (!BIASROW && bias) bb = bias[n0 + lcol];
                        #pragma unroll
                        for (int j = 0; j < 4; ++j) {
                            float v = acc[mi][ni][j] + (BIASROW ? bias[r0 + j] : bb);
                            if (doElu) v = (v > 0.0f) ? (v + 1.0f) : __expf(v);
                            lt[(lrow + j) * 132 + lcol] = v;
                        }
                    }
                }
            }
            __builtin_amdgcn_s_barrier();
            #pragma unroll
            for (int it = 0; it < 4; ++it) {
                const int chk = it * 256 + tid;    // 0..1023
                const int r   = chk >> 5;          // 0..31
                const int g   = chk & 31;
                float4 v = *(const float4*)(lt + r * 132 + g * 4);
                *(float4*)((float*)Cout + cb + (m0 + q * 32 + r) * ldc + n0 + g * 4) = v;
            }
        }
    } else {
        // bf16: 2 rounds of 64-row chunks [64][136] bf16 (17.4KB)
        bf16* lt = (bf16*)smem;
        #pragma unroll
        for (int h = 0; h < 2; ++h) {
            __builtin_amdgcn_s_barrier();
            if (wr == h) {
                #pragma unroll
                for (int mi = 0; mi < 4; ++mi) {
                    const int lrow = mi * 16 + crow;           // 0..60
                    const long long r0 = m0 + h * 64 + lrow;
                    #pragma unroll
                    for (int ni = 0; ni < 4; ++ni) {
                        const int lcol = wc * 64 + ni * 16 + la15;
                        float bb = 0.0f;
                        if (!BIASROW && bias) bb = bias[n0 + lcol];
                        #pragma unroll
                        for (int j = 0; j < 4; ++j) {
                            float v = acc[mi][ni][j] + (BIASROW ? bias[r0 + j] : bb);
                            if (doElu) v = (v > 0.0f) ? (v + 1.0f) : __expf(v);
                            lt[(lrow + j) * 136 + lcol] = (bf16)v;
                        }
                    }
                }
            }
            __builtin_amdgcn_s_barrier();
            #pragma unroll
            for (int it = 0; it < 4; ++it) {
                const int chk = it * 256 + tid;    // 0..1023
                const int m   = chk >> 4;          // 0..63 (16 granules/row)
                const int nof = (chk & 15) * 8;
                bf16x8 v = *(const bf16x8*)(lt + m * 136 + nof);
                *(bf16x8*)((bf16*)Cout + cb + (m0 + h * 64 + m) * ldc + n0 + nof) = v;
            }
        }
    }
}

// ---------------- launch ----------------
extern "C" void kernel_launch(void* const* d_in, const int* in_sizes, int n_in,
                              void* d_out, int out_size, void* d_ws, size_t ws_size,
                              hipStream_t stream)
{
    const float* x  = (const float*)d_in[0];
    const float* Wq = (const float*)d_in[1];
    const float* bq = (const float*)d_in[2];
    const float* Wk = (const float*)d_in[3];
    const float* bk = (const float*)d_in[4];
    const float* Wv = (const float*)d_in[5];
    const float* bv = (const float*)d_in[6];
    const float* Wo = (const float*)d_in[7];
    const float* bo = (const float*)d_in[8];
    float* out = (float*)d_out;

    // ws layout (152 MiB):
    //  [0,64M)    xbp [b][s][d]
    //  [64M,128M) KVo partials (32MB) -> then Qb [b][s][d] (partials dead by then)
    //  [128M,144M) wvT(2MB)+bkvo(8KB) temps -> then KVo (16MB; temps dead)
    //  [144M,152M) wqb(2MB) wob(2MB) wkvo(4MB = [Wk;Wvo] 2048x1024)
    char* ws = (char*)d_ws;
    if (ws_size < (size_t)159383552) return;
    bf16*  xbp  = (bf16*)(ws + 0);
    bf16*  part = (bf16*)(ws + 67108864);
    bf16*  Qb   = (bf16*)(ws + 67108864);
    bf16*  wvT  = (bf16*)(ws + 134217728);
    float* bkvo = (float*)(ws + 134217728 + 2097152);
    bf16*  KVo  = (bf16*)(ws + 134217728);
    bf16*  wqb  = (bf16*)(ws + 150994944);
    bf16*  wob  = wqb + 1048576;
    bf16*  wkvo = wob + 1048576;           // [2048][1024]: rows 0-1023 Wk, 1024-2047 Wvo
    bf16*  KVb  = (bf16*)d_out;            // [b][2048][S]: rows 0-1023 Kt, 1024-2047 Vt'

    const long long SD = (long long)S * D;

    // 1) converts + folded-weight prep
    cvt_permute<<<8192, 256, 0, stream>>>(x, xbp);
    cvt_f32_to_bf16<<<1024, 256, 0, stream>>>(Wq, wqb, D * D);
    cvt_f32_to_bf16<<<1024, 256, 0, stream>>>(Wo, wob, D * D);
    cvt_f32_to_bf16<<<1024, 256, 0, stream>>>(Wk, wkvo, D * D);
    cvt_transpose_1024<<<dim3(16, 16), 256, 0, stream>>>(Wv, wvT);
    bvo_kernel<<<1024, 256, 0, stream>>>(Wo, bv, bkvo + 1024);
    hipMemcpyAsync(bkvo, bk, D * sizeof(float), hipMemcpyDeviceToDevice, stream);

    // 2) Wvo rows: wkvo[1024+e'][d] = sum_e Wo[e'][e] Wv[e][d]
    gemm_bt<128, 128, 2, 2, 0, 0, 0><<<dim3(8, 8, 1), 256, 0, stream>>>(
        wob, wvT, nullptr, wkvo + (long long)1024 * 1024, D, D, D, D, 0, 0, 0);

    // 3) fused K|V' projection: KVb[b][r][s] = [Wk;Wvo] @ xbp_b^T, elu+1 for r<1024
    //    128^2 tile, GROUPN=1 (chunks share xbp B-panels)
    gemm_r128<2, 0, 1, 1><<<dim3(32, 16, 8), 256, 0, stream>>>(
        wkvo, xbp, bkvo, KVb, D, D, S, D,
        0, SD, (long long)2048 * S);

    // 4) KVo partials: part[2b+h][e'][d] = sum_{s half h} Vt'[b][e'][s] Kt[b][d][s]
    gemm8p<0, 0, 0, 2, 0><<<dim3(4, 4, 16), 512, 0, stream>>>(
        KVb + (long long)1024 * S, KVb, nullptr, part, S, S, D, 2048,
        (long long)2048 * S, (long long)2048 * S, (long long)D * D);

    // 5) KVo = part0 + part1
    kv_add<<<dim3(512, 8), 256, 0, stream>>>(part, KVo);

    // 6) Qb[b][s][d] = elu(xbp_b Wq^T + bq)+1  (overwrites partials — dead)
    gemm_r128<1, 0, 0, 0><<<dim3(8, 32, 8), 256, 0, stream>>>(
        xbp, wqb, bq, Qb, D, D, D, D, SD, 0, SD);

    // 7) out[s][b][e'] = Qb[b] @ KVo[b]^T + bo  (fp32; C row s at b*D offset)
    gemm_r128<0, 1, 0, 0><<<dim3(8, 32, 8), 256, 0, stream>>>(
        Qb, KVo, bo, out, D, D, B * D, D,
        SD, (long long)D * D, (long long)D);
}

// Round 14
// 483.412 us; speedup vs baseline: 8.9277x; 1.0698x over previous
//
#include <hip/hip_runtime.h>

// LinearAttention, S=4096 B=8 D=1024.  (R11 consolidation — best measured 487us)
// out = Q @ (K^T V')_b^T + bo, V' = x Wvo^T + bvo, Wvo = Wo Wv (folded).
// x permuted to [b][s][d]; fused K|V' proj -> KVb [b][2048][s]; split-K2 KVo.
// 256^2 GEMM, 8 phases/iter x 16 MFMA, ONE barrier per phase, reads+MFMA
// compiler-interleaved (counted lgkm), vmcnt(6) gates at P3/P7.
// LDS epilogues (bf16 512B runs / fp32 float4 runs). Weight converts merged.

typedef __bf16 bf16;
typedef __attribute__((ext_vector_type(8))) __bf16 bf16x8;
typedef __attribute__((ext_vector_type(4))) __bf16 bf16x4;
typedef __attribute__((ext_vector_type(4))) float f32x4;

static constexpr int S = 4096;
static constexpr int B = 8;
static constexpr int D = 1024;
static constexpr int SB = S * B;
static constexpr long long NELEM = (long long)SB * D;

__device__ __forceinline__ void load_lds16(const bf16* g, void* l)
{
    __builtin_amdgcn_global_load_lds(
        (const __attribute__((address_space(1))) void*)g,
        (__attribute__((address_space(3))) void*)l, 16, 0, 0);
}

// ---------------- 3x weight fp32 -> bf16 convert (merged) ----------------
__global__ void cvt_w3(const float* __restrict__ w0, const float* __restrict__ w1,
                       const float* __restrict__ w2, bf16* __restrict__ o0,
                       bf16* __restrict__ o1, bf16* __restrict__ o2)
{
    const float* in;
    bf16* out;
    if (blockIdx.y == 0)      { in = w0; out = o0; }
    else if (blockIdx.y == 1) { in = w1; out = o1; }
    else                      { in = w2; out = o2; }
    int i = (blockIdx.x * blockDim.x + threadIdx.x) * 4;
    float4 v = *(const float4*)(in + i);
    bf16x4 o;
    o[0] = (bf16)v.x; o[1] = (bf16)v.y; o[2] = (bf16)v.z; o[3] = (bf16)v.w;
    *(bf16x4*)(out + i) = o;
}

// ---------------- x [S][B][D] fp32 -> xbp [B][S][D] bf16 ----------------
__global__ void cvt_permute(const float* __restrict__ in, bf16* __restrict__ out)
{
    long long i = ((long long)blockIdx.x * blockDim.x + threadIdx.x) * 8;
    const long long stride = (long long)gridDim.x * blockDim.x * 8;
    for (; i < NELEM; i += stride) {
        const long long s = i >> 13;
        const long long r = i & 8191;
        const long long b = r >> 10;
        const long long d = r & 1023;
        float4 v0 = *(const float4*)(in + i);
        float4 v1 = *(const float4*)(in + i + 4);
        bf16x8 o;
        o[0] = (bf16)v0.x; o[1] = (bf16)v0.y; o[2] = (bf16)v0.z; o[3] = (bf16)v0.w;
        o[4] = (bf16)v1.x; o[5] = (bf16)v1.y; o[6] = (bf16)v1.z; o[7] = (bf16)v1.w;
        *(bf16x8*)(out + b * ((long long)S * D) + s * D + d) = o;
    }
}

// ---------------- Wv (fp32 [e][d]) -> WvT (bf16 [d][e]) ----------------
__global__ __launch_bounds__(256) void cvt_transpose_1024(
    const float* __restrict__ in, bf16* __restrict__ out)
{
    __shared__ bf16 tile[64][72];
    const int e0 = blockIdx.y * 64;
    const int d0 = blockIdx.x * 64;
    const int t  = threadIdx.x;
    const int rl = t >> 3;
    const int c8 = (t & 7) * 8;
    #pragma unroll
    for (int p = 0; p < 2; ++p) {
        int r = rl + p * 32;
        float4 v0 = *(const float4*)(in + (long long)(e0 + r) * D + d0 + c8);
        float4 v1 = *(const float4*)(in + (long long)(e0 + r) * D + d0 + c8 + 4);
        tile[c8+0][r] = (bf16)v0.x; tile[c8+1][r] = (bf16)v0.y;
        tile[c8+2][r] = (bf16)v0.z; tile[c8+3][r] = (bf16)v0.w;
        tile[c8+4][r] = (bf16)v1.x; tile[c8+5][r] = (bf16)v1.y;
        tile[c8+6][r] = (bf16)v1.z; tile[c8+7][r] = (bf16)v1.w;
    }
    __syncthreads();
    #pragma unroll
    for (int p = 0; p < 2; ++p) {
        int dr = rl + p * 32;
        *(bf16x8*)(out + (long long)(d0 + dr) * D + e0 + c8) = *(bf16x8*)(&tile[dr][c8]);
    }
}

// ---------------- bvo = Wo @ bv (fp32) ----------------
__global__ __launch_bounds__(256) void bvo_kernel(
    const float* __restrict__ Wo, const float* __restrict__ bv, float* __restrict__ bvo)
{
    const int row = blockIdx.x;
    const int t = threadIdx.x;
    float4 w = *(const float4*)(Wo + (long long)row * D + t * 4);
    float4 b = *(const float4*)(bv + t * 4);
    float s = w.x*b.x + w.y*b.y + w.z*b.z + w.w*b.w;
    __shared__ float red[256];
    red[t] = s; __syncthreads();
    for (int off = 128; off > 0; off >>= 1) {
        if (t < off) red[t] += red[t + off];
        __syncthreads();
    }
    if (t == 0) bvo[row] = red[0];
}

// ---------------- KVo = part0 + part1 (bf16) ----------------
__global__ __launch_bounds__(256) void kv_add(const bf16* __restrict__ p, bf16* __restrict__ o)
{
    const long long DD = (long long)D * D;
    const int b = blockIdx.y;
    const long long i = ((long long)blockIdx.x * 256 + threadIdx.x) * 8;
    bf16x8 u = *(const bf16x8*)(p + (2 * b) * DD + i);
    bf16x8 v = *(const bf16x8*)(p + (2 * b + 1) * DD + i);
    bf16x8 r;
    #pragma unroll
    for (int j = 0; j < 8; ++j) r[j] = (bf16)((float)u[j] + (float)v[j]);
    *(bf16x8*)(o + b * DD + i) = r;
}

// ---------------- R3 ring GEMM (small shapes: Wvo only) ----------------
template<int BM, int BN, int WM, int WN, int EPI, int OUTF32, int BIASROW>
__global__ __launch_bounds__(WM * WN * 64, 2) void gemm_bt(
    const bf16* __restrict__ A, const bf16* __restrict__ Bm,
    const float* __restrict__ bias, void* __restrict__ Cout,
    int lda, int ldb, int ldc, int K,
    long long aBatch, long long bBatch, long long cBatch)
{
    constexpr int THREADS = WM * WN * 64;
    constexpr int WROWS = BM / WM, WCOLS = BN / WN;
    constexpr int MI = WROWS / 16, NI = WCOLS / 16;
    constexpr int ABYTES = BM * 64;
    constexpr int BBYTES = BN * 64;
    constexpr int BUF = ABYTES + BBYTES;

    __shared__ unsigned char smem[4 * BUF];

    const int tid  = threadIdx.x;
    const int lane = tid & 63;
    const int wave = tid >> 6;
    const int wr   = wave / WN;
    const int wc   = wave % WN;
    const int bz   = blockIdx.z;

    const int nx  = gridDim.x;
    const int bid = blockIdx.y * nx + blockIdx.x;
    const int cpx = (nx * gridDim.y) >> 3;
    const int swz = (bid & 7) * cpx + (bid >> 3);
    const long long m0 = (long long)(swz / nx) * BM;
    const long long n0 = (long long)(swz % nx) * BN;

    const bf16* Ab = A  + bz * aBatch + m0 * lda;
    const bf16* Bb = Bm + bz * bBatch + n0 * ldb;

    f32x4 acc[MI][NI] = {};
    const int NT = K >> 5;

    auto stage = [&](int t) {
        unsigned char* dst = smem + (t & 3) * BUF;
        const long long kk = (long long)t << 5;
        #pragma unroll
        for (int j = 0; j < 2; ++j) {
            const int g  = wave * 64 + lane + j * THREADS;
            const int gs = g ^ ((g >> 3) & 3);
            const int row = gs >> 2, col = (gs & 3) * 8;
            load_lds16(Ab + (long long)row * lda + kk + col,
                       dst + (wave * 64 + j * THREADS) * 16);
        }
        #pragma unroll
        for (int j = 0; j < 2; ++j) {
            const int g  = wave * 64 + lane + j * THREADS;
            const int gs = g ^ ((g >> 3) & 3);
            const int row = gs >> 2, col = (gs & 3) * 8;
            load_lds16(Bb + (long long)row * ldb + kk + col,
                       dst + ABYTES + (wave * 64 + j * THREADS) * 16);
        }
    };

    stage(0); stage(1); stage(2);

    const int ko2 = (lane >> 4) * 16;
    const int la15 = lane & 15;

    for (int t = 0; t < NT; ++t) {
        if (t + 2 < NT)      asm volatile("s_waitcnt vmcnt(8)" ::: "memory");
        else if (t + 1 < NT) asm volatile("s_waitcnt vmcnt(4)" ::: "memory");
        else                 asm volatile("s_waitcnt vmcnt(0)" ::: "memory");
        __builtin_amdgcn_s_barrier();
        asm volatile("" ::: "memory");

        if (t + 3 < NT) stage(t + 3);

        const unsigned char* buf = smem + (t & 3) * BUF;
        bf16x8 a[MI], b[NI];
        #pragma unroll
        for (int mi = 0; mi < MI; ++mi) {
            int ad = (wr * WROWS + mi * 16 + la15) * 64 + ko2;
            ad ^= ((ad >> 7) & 3) << 4;
            a[mi] = *(const bf16x8*)(buf + ad);
        }
        #pragma unroll
        for (int ni = 0; ni < NI; ++ni) {
            int ad = (wc * WCOLS + ni * 16 + la15) * 64 + ko2;
            ad ^= ((ad >> 7) & 3) << 4;
            b[ni] = *(const bf16x8*)(buf + ABYTES + ad);
        }

        __builtin_amdgcn_s_setprio(1);
        #pragma unroll
        for (int mi = 0; mi < MI; ++mi)
            #pragma unroll
            for (int ni = 0; ni < NI; ++ni)
                acc[mi][ni] = __builtin_amdgcn_mfma_f32_16x16x32_bf16(
                    a[mi], b[ni], acc[mi][ni], 0, 0, 0);
        __builtin_amdgcn_s_setprio(0);
    }

    const int crow = (lane >> 4) * 4;
    const int ccol = lane & 15;
    #pragma unroll
    for (int ni = 0; ni < NI; ++ni) {
        const long long c = n0 + wc * WCOLS + ni * 16 + ccol;
        float bcol = 0.0f;
        if (!BIASROW && bias) bcol = bias[c];
        #pragma unroll
        for (int mi = 0; mi < MI; ++mi) {
            const long long r0 = m0 + wr * WROWS + mi * 16 + crow;
            #pragma unroll
            for (int j = 0; j < 4; ++j) {
                float v = acc[mi][ni][j];
                v += BIASROW ? bias[r0 + j] : bcol;
                if (EPI == 1) v = (v > 0.0f) ? (v + 1.0f) : __expf(v);
                const long long idx = bz * cBatch + (r0 + j) * ldc + c;
                if (OUTF32) ((float*)Cout)[idx] = v;
                else        ((bf16*)Cout)[idx]  = (bf16)v;
            }
        }
    }
}

// ---------------- 256^2 8-phase GEMM, single barrier/phase (R11) ----------------
// BM=BN=256, BK=64, 512 thr = 8 waves (2M x 4N), per-wave 128x64.
// Phase p: {s_barrier; sched_barrier(0); ds-reads + 16 MFMA (compiler
// interleaves counted lgkm waits); stage slot; gate}. Gates: P3/P7 vmcnt(6),
// last-iter P3 vmcnt(0). Every stage slot targets a region last read in the
// PREVIOUS phase -> the single barrier makes the overwrite race-free.
// EPI: 1 = elu+1; 2 = elu+1 iff m0 < 1024. SPLITK: z = batch*SPLITK + kseg.
// GROUPN: 0 = row-major tile enum (A reuse); 1 = col-major (B reuse).
template<int EPI, int OUTF32, int BIASROW, int SPLITK, int GROUPN>
__global__ __launch_bounds__(512, 1) void gemm8p(
    const bf16* __restrict__ A, const bf16* __restrict__ Bm,
    const float* __restrict__ bias, void* __restrict__ Cout,
    int lda, int ldb, int ldc, int K,
    long long aBatch, long long bBatch, long long cBatch)
{
    __shared__ unsigned char smem[131072];

    const int tid  = threadIdx.x;
    const int lane = tid & 63;
    const int wave = tid >> 6;
    const int wr   = wave >> 2;
    const int wc   = wave & 3;
    const int bz    = blockIdx.z;
    const int batch = bz / SPLITK;
    const int kseg  = bz % SPLITK;

    const int nx  = gridDim.x;
    const int ny  = gridDim.y;
    const int bid = blockIdx.y * nx + blockIdx.x;
    const int cpx = (nx * ny) >> 3;
    const int swzb = (bid & 7) * cpx + (bid >> 3);
    long long m0, n0;
    if (GROUPN) { n0 = (long long)(swzb / ny) * 256; m0 = (long long)(swzb % ny) * 256; }
    else        { m0 = (long long)(swzb / nx) * 256; n0 = (long long)(swzb % nx) * 256; }

    const bf16* Ab = A  + batch * aBatch + m0 * lda + (long long)kseg * K;
    const bf16* Bb = Bm + batch * bBatch + n0 * ldb + (long long)kseg * K;

    const int sg = (lane & 3) ^ ((lane >> 3) & 3);
    const long long srow = wave * 32 + (lane >> 2);
    const bf16* srcA  = Ab + srow * lda + sg * 8;
    const bf16* srcA2 = srcA + 16 * (long long)lda;
    const bf16* srcB  = Bb + srow * ldb + sg * 8;
    const bf16* srcB2 = srcB + 16 * (long long)ldb;
    const int dstoff = wave * 2048;

    const int la15 = lane & 15;
    const int rsw  = (lane >> 4) ^ ((la15 >> 1) & 3);
    const int a16  = (wr * 128 + la15) * 4 + rsw;
    const int b16  = (wc * 64  + la15) * 4 + rsw;

    f32x4 acc[8][4] = {};
    const int NT = K >> 6;
    const int NI = NT >> 1;

    auto stageA = [&](int T, int kh) {
        const int reg = ((((T & 1) << 1) | kh) << 14);
        const long long kp = ((long long)T << 6) + (kh << 5);
        load_lds16(srcA  + kp, smem + reg + dstoff);
        load_lds16(srcA2 + kp, smem + reg + dstoff + 1024);
    };
    auto stageB = [&](int T, int kh) {
        const int reg = 65536 + ((((T & 1) << 1) | kh) << 14);
        const long long kp = ((long long)T << 6) + (kh << 5);
        load_lds16(srcB  + kp, smem + reg + dstoff);
        load_lds16(srcB2 + kp, smem + reg + dstoff + 1024);
    };

    // prologue: tile0 fully + tile1 {Bk0,Ak0,Bk1}; A(1,1) staged in iter-0 P0.
    // vmcnt(6): 14 outstanding -> oldest 8 = all of tile 0.
    stageB(0, 0); stageA(0, 0); stageB(0, 1); stageA(0, 1);
    stageB(1, 0); stageA(1, 0); stageB(1, 1);
    asm volatile("s_waitcnt vmcnt(6)" ::: "memory");

    bf16x8 bfr[4];
    for (int i = 0; i < NI; ++i) {
        const int t = 2 * i;
        const bool nl = (i + 1 < NI);
        #pragma unroll
        for (int p = 0; p < 8; ++p) {
            const int ks  = (p >> 1) & 1;
            const int ch  = p & 1;
            const int buf = p >> 2;
            const int regA = ((buf << 1) | ks) << 14;
            const int regB = 65536 + regA;

            // phase boundary: one barrier; pin everything below it
            __builtin_amdgcn_s_barrier();
            __builtin_amdgcn_sched_barrier(0);

            // ds-reads (plain loads -> compiler interleaves with MFMAs below)
            bf16x8 afr[4];
            if (ch == 0) {
                #pragma unroll
                for (int ni = 0; ni < 4; ++ni)
                    bfr[ni] = *(const bf16x8*)(smem + regB + (b16 + ni * 64) * 16);
            }
            #pragma unroll
            for (int m4 = 0; m4 < 4; ++m4)
                afr[m4] = *(const bf16x8*)(smem + regA + (a16 + (ch * 4 + m4) * 64) * 16);

            // stage slot (one half-tile = 2 gload_lds); target region was
            // last read in the PREVIOUS phase -> barrier-protected
            if      (p == 0) stageA(t + 1, 1);
            else if (p == 1) { if (t + 2 < NT) stageB(t + 2, 0); }
            else if (p == 2) { if (t + 2 < NT) stageA(t + 2, 0); }
            else if (p == 3) { if (t + 2 < NT) stageB(t + 2, 1); }
            else if (p == 4) { if (t + 2 < NT) stageA(t + 2, 1); }
            else if (p == 5) { if (t + 3 < NT) stageB(t + 3, 0); }
            else if (p == 6) { if (t + 3 < NT) stageA(t + 3, 0); }
            else             { if (t + 3 < NT) stageB(t + 3, 1); }

            // counted gate once per K-tile (before next phase's barrier)
            if (p == 3) {
                if (nl) asm volatile("s_waitcnt vmcnt(6)" ::: "memory");
                else    asm volatile("s_waitcnt vmcnt(0)" ::: "memory");
            } else if (p == 7) {
                if (nl) asm volatile("s_waitcnt vmcnt(6)" ::: "memory");
            }

            // MFMA cluster (compiler inserts counted lgkm waits vs reads)
            __builtin_amdgcn_s_setprio(1);
            #pragma unroll
            for (int m4 = 0; m4 < 4; ++m4)
                #pragma unroll
                for (int ni = 0; ni < 4; ++ni)
                    acc[ch * 4 + m4][ni] = __builtin_amdgcn_mfma_f32_16x16x32_bf16(
                        afr[m4], bfr[ni], acc[ch * 4 + m4][ni], 0, 0, 0);
            __builtin_amdgcn_s_setprio(0);
        }
    }

    // ---- epilogue (all paths via LDS for contiguous stores) ----
    const bool doElu = (EPI == 1) || (EPI == 2 && m0 < 1024);
    const long long cb = (long long)bz * cBatch;
    const int crow = (lane >> 4) * 4;

    if constexpr (OUTF32 != 0) {
        // fp32: 64-row quarter-tiles in LDS [64][260] f32; 256B float4 stores
        float* lt = (float*)smem;
        #pragma unroll
        for (int q = 0; q < 4; ++q) {
            __builtin_amdgcn_s_barrier();
            __builtin_amdgcn_sched_barrier(0);
            if (wr == (q >> 1)) {
                #pragma unroll
                for (int m4 = 0; m4 < 4; ++m4) {
                    const int mi = (q & 1) * 4 + m4;
                    const int lrow = m4 * 16 + crow;
                    const long long r0 = m0 + q * 64 + lrow;
                    #pragma unroll
                    for (int ni = 0; ni < 4; ++ni) {
                        const int lcol = wc * 64 + ni * 16 + la15;
                        float bb = 0.0f;
                        if (!BIASROW && bias) bb = bias[n0 + lcol];
                        #pragma unroll
                        for (int j = 0; j < 4; ++j) {
                            float v = acc[mi][ni][j] + (BIASROW ? bias[r0 + j] : bb);
                            if (doElu) v = (v > 0.0f) ? (v + 1.0f) : __expf(v);
                            lt[(lrow + j) * 260 + lcol] = v;
                        }
                    }
                }
            }
            __builtin_amdgcn_s_barrier();
            #pragma unroll
            for (int it = 0; it < 8; ++it) {
                const int chk = it * 512 + tid;
                const int r   = chk >> 6;
                const int g   = chk & 63;
                float4 v = *(const float4*)(lt + r * 260 + g * 4);
                *(float4*)((float*)Cout + cb + (m0 + q * 64 + r) * ldc + n0 + g * 4) = v;
            }
        }
    } else {
        // bf16: 128-row half-tiles in LDS [m][264]; 512B-contiguous stores
        bf16* lt = (bf16*)smem;
        #pragma unroll
        for (int half = 0; half < 2; ++half) {
            __builtin_amdgcn_s_barrier();
            __builtin_amdgcn_sched_barrier(0);
            if (wr == half) {
                #pragma unroll
                for (int mi = 0; mi < 8; ++mi) {
                    const int lrow = mi * 16 + crow;
                    const long long r0 = m0 + half * 128 + lrow;
                    #pragma unroll
                    for (int ni = 0; ni < 4; ++ni) {
                        const int lcol = wc * 64 + ni * 16 + la15;
                        float bb = 0.0f;
                        if (!BIASROW && bias) bb = bias[n0 + lcol];
                        #pragma unroll
                        for (int j = 0; j < 4; ++j) {
                            float v = acc[mi][ni][j] + (BIASROW ? bias[r0 + j] : bb);
                            if (doElu) v = (v > 0.0f) ? (v + 1.0f) : __expf(v);
                            lt[(lrow + j) * 264 + lcol] = (bf16)v;
                        }
                    }
                }
            }
            __builtin_amdgcn_s_barrier();
            #pragma unroll
            for (int it = 0; it < 8; ++it) {
                const int chk = it * 512 + tid;
                const int m   = chk >> 5;
                const int nof = (chk & 31) * 8;
                bf16x8 v = *(const bf16x8*)(lt + m * 264 + nof);
                *(bf16x8*)((bf16*)Cout + cb + (m0 + half * 128 + m) * ldc + n0 + nof) = v;
            }
        }
    }
}

// ---------------- launch ----------------
extern "C" void kernel_launch(void* const* d_in, const int* in_sizes, int n_in,
                              void* d_out, int out_size, void* d_ws, size_t ws_size,
                              hipStream_t stream)
{
    const float* x  = (const float*)d_in[0];
    const float* Wq = (const float*)d_in[1];
    const float* bq = (const float*)d_in[2];
    const float* Wk = (const float*)d_in[3];
    const float* bk = (const float*)d_in[4];
    const float* Wv = (const float*)d_in[5];
    const float* bv = (const float*)d_in[6];
    const float* Wo = (const float*)d_in[7];
    const float* bo = (const float*)d_in[8];
    float* out = (float*)d_out;

    // ws layout (152 MiB):
    //  [0,64M)    xbp [b][s][d]
    //  [64M,128M) KVo partials (32MB) -> then Qb [b][s][d] (partials dead by then)
    //  [128M,144M) wvT(2MB)+bkvo(8KB) temps -> then KVo (16MB; temps dead)
    //  [144M,152M) wqb(2MB) wob(2MB) wkvo(4MB = [Wk;Wvo] 2048x1024)
    char* ws = (char*)d_ws;
    if (ws_size < (size_t)159383552) return;
    bf16*  xbp  = (bf16*)(ws + 0);
    bf16*  part = (bf16*)(ws + 67108864);
    bf16*  Qb   = (bf16*)(ws + 67108864);
    bf16*  wvT  = (bf16*)(ws + 134217728);
    float* bkvo = (float*)(ws + 134217728 + 2097152);
    bf16*  KVo  = (bf16*)(ws + 134217728);
    bf16*  wqb  = (bf16*)(ws + 150994944);
    bf16*  wob  = wqb + 1048576;
    bf16*  wkvo = wob + 1048576;           // [2048][1024]: rows 0-1023 Wk, 1024-2047 Wvo
    bf16*  KVb  = (bf16*)d_out;            // [b][2048][S]: rows 0-1023 Kt, 1024-2047 Vt'

    const long long SD = (long long)S * D;

    // 1) converts + folded-weight prep (weight converts merged into one launch)
    cvt_permute<<<8192, 256, 0, stream>>>(x, xbp);
    cvt_w3<<<dim3(1024, 3), 256, 0, stream>>>(Wq, Wo, Wk, wqb, wob, wkvo);
    cvt_transpose_1024<<<dim3(16, 16), 256, 0, stream>>>(Wv, wvT);
    bvo_kernel<<<1024, 256, 0, stream>>>(Wo, bv, bkvo + 1024);
    hipMemcpyAsync(bkvo, bk, D * sizeof(float), hipMemcpyDeviceToDevice, stream);

    // 2) Wvo rows: wkvo[1024+e'][d] = sum_e Wo[e'][e] Wv[e][d]
    gemm_bt<128, 128, 2, 2, 0, 0, 0><<<dim3(8, 8, 1), 256, 0, stream>>>(
        wob, wvT, nullptr, wkvo + (long long)1024 * 1024, D, D, D, D, 0, 0, 0);

    // 3) fused K|V' projection: KVb[b][r][s] = [Wk;Wvo] @ xbp_b^T, elu+1 for r<1024
    gemm8p<2, 0, 1, 1, 1><<<dim3(16, 8, 8), 512, 0, stream>>>(
        wkvo, xbp, bkvo, KVb, D, D, S, D,
        0, SD, (long long)2048 * S);

    // 4) KVo partials: part[2b+h][e'][d] = sum_{s half h} Vt'[b][e'][s] Kt[b][d][s]
    gemm8p<0, 0, 0, 2, 0><<<dim3(4, 4, 16), 512, 0, stream>>>(
        KVb + (long long)1024 * S, KVb, nullptr, part, S, S, D, 2048,
        (long long)2048 * S, (long long)2048 * S, (long long)D * D);

    // 5) KVo = part0 + part1
    kv_add<<<dim3(512, 8), 256, 0, stream>>>(part, KVo);

    // 6) Qb[b][s][d] = elu(xbp_b Wq^T + bq)+1  (overwrites partials — dead)
    gemm8p<1, 0, 0, 1, 0><<<dim3(4, 16, 8), 512, 0, stream>>>(
        xbp, wqb, bq, Qb, D, D, D, D, SD, 0, SD);

    // 7) out[s][b][e'] = Qb[b] @ KVo[b]^T + bo  (fp32; C row s at b*D offset)
    gemm8p<0, 1, 0, 1, 0><<<dim3(4, 16, 8), 512, 0, stream>>>(
        Qb, KVo, bo, out, D, D, B * D, D,
        SD, (long long)D * D, (long long)D);
}

// Round 15
// 467.502 us; speedup vs baseline: 9.2315x; 1.0340x over previous
//
#include <hip/hip_runtime.h>

// LinearAttention, S=4096 B=8 D=1024.
// Algebraic form: K = elu(Wk x^T + bk)+1 (only nonlinear proj materialized);
//   MT[b][d][f] = sum_s K[s,d] x[s,f];  KVo = Wvo*MT^T + bvo (x) Ksum;
//   out = (elu(x Wq^T + bq)+1) @ KVo^T + bo.   Wvo = Wo Wv, bvo = Wo bv.
// gemm8p: 256^2, 8 phases/iter, 1 barrier/phase, vmcnt(6)@P3/P7 (R11-verified).
// LDS epilogues (bf16 512B runs / fp32 float4 runs).

typedef __bf16 bf16;
typedef __attribute__((ext_vector_type(8))) __bf16 bf16x8;
typedef __attribute__((ext_vector_type(4))) __bf16 bf16x4;
typedef __attribute__((ext_vector_type(4))) float f32x4;

static constexpr int S = 4096;
static constexpr int B = 8;
static constexpr int D = 1024;
static constexpr int SB = S * B;
static constexpr long long NELEM = (long long)SB * D;

__device__ __forceinline__ void load_lds16(const bf16* g, void* l)
{
    __builtin_amdgcn_global_load_lds(
        (const __attribute__((address_space(1))) void*)g,
        (__attribute__((address_space(3))) void*)l, 16, 0, 0);
}

// ---------------- 3x weight fp32 -> bf16 convert (merged) ----------------
__global__ void cvt_w3(const float* __restrict__ w0, const float* __restrict__ w1,
                       const float* __restrict__ w2, bf16* __restrict__ o0,
                       bf16* __restrict__ o1, bf16* __restrict__ o2)
{
    const float* in;
    bf16* out;
    if (blockIdx.y == 0)      { in = w0; out = o0; }
    else if (blockIdx.y == 1) { in = w1; out = o1; }
    else                      { in = w2; out = o2; }
    int i = (blockIdx.x * blockDim.x + threadIdx.x) * 4;
    float4 v = *(const float4*)(in + i);
    bf16x4 o;
    o[0] = (bf16)v.x; o[1] = (bf16)v.y; o[2] = (bf16)v.z; o[3] = (bf16)v.w;
    *(bf16x4*)(out + i) = o;
}

// ---------------- x [S][B][D] fp32 -> xbp [B][S][D] bf16 ----------------
__global__ void cvt_permute(const float* __restrict__ in, bf16* __restrict__ out)
{
    long long i = ((long long)blockIdx.x * blockDim.x + threadIdx.x) * 8;
    const long long stride = (long long)gridDim.x * blockDim.x * 8;
    for (; i < NELEM; i += stride) {
        const long long s = i >> 13;
        const long long r = i & 8191;
        const long long b = r >> 10;
        const long long d = r & 1023;
        float4 v0 = *(const float4*)(in + i);
        float4 v1 = *(const float4*)(in + i + 4);
        bf16x8 o;
        o[0] = (bf16)v0.x; o[1] = (bf16)v0.y; o[2] = (bf16)v0.z; o[3] = (bf16)v0.w;
        o[4] = (bf16)v1.x; o[5] = (bf16)v1.y; o[6] = (bf16)v1.z; o[7] = (bf16)v1.w;
        *(bf16x8*)(out + b * ((long long)S * D) + s * D + d) = o;
    }
}

// ---------------- xbp [b][s][f] -> xT [b][f][s] (bf16 transpose) ----------------
__global__ __launch_bounds__(256) void transpose_bsd_bds(
    const bf16* __restrict__ in, bf16* __restrict__ out)
{
    __shared__ bf16 tile[64 * 72];
    const int b  = blockIdx.z;
    const int s0 = blockIdx.x * 64;
    const int f0 = blockIdx.y * 64;
    const int t  = threadIdx.x;
    const int rl = t >> 3;
    const int c8 = (t & 7) * 8;
    const long long SD = (long long)S * D;

    #pragma unroll
    for (int p = 0; p < 2; ++p) {
        int r = rl + p * 32;
        bf16x8 v = *(const bf16x8*)(in + b * SD + (long long)(s0 + r) * D + f0 + c8);
        #pragma unroll
        for (int j = 0; j < 8; ++j)
            tile[(c8 + j) * 72 + r] = v[j];
    }
    __syncthreads();
    #pragma unroll
    for (int p = 0; p < 2; ++p) {
        int fr = rl + p * 32;
        *(bf16x8*)(out + b * SD + (long long)(f0 + fr) * S + s0 + c8) =
            *(const bf16x8*)(&tile[fr * 72 + c8]);
    }
}

// ---------------- Wv (fp32 [e][d]) -> WvT (bf16 [d][e]) ----------------
__global__ __launch_bounds__(256) void cvt_transpose_1024(
    const float* __restrict__ in, bf16* __restrict__ out)
{
    __shared__ bf16 tile[64][72];
    const int e0 = blockIdx.y * 64;
    const int d0 = blockIdx.x * 64;
    const int t  = threadIdx.x;
    const int rl = t >> 3;
    const int c8 = (t & 7) * 8;
    #pragma unroll
    for (int p = 0; p < 2; ++p) {
        int r = rl + p * 32;
        float4 v0 = *(const float4*)(in + (long long)(e0 + r) * D + d0 + c8);
        float4 v1 = *(const float4*)(in + (long long)(e0 + r) * D + d0 + c8 + 4);
        tile[c8+0][r] = (bf16)v0.x; tile[c8+1][r] = (bf16)v0.y;
        tile[c8+2][r] = (bf16)v0.z; tile[c8+3][r] = (bf16)v0.w;
        tile[c8+4][r] = (bf16)v1.x; tile[c8+5][r] = (bf16)v1.y;
        tile[c8+6][r] = (bf16)v1.z; tile[c8+7][r] = (bf16)v1.w;
    }
    __syncthreads();
    #pragma unroll
    for (int p = 0; p < 2; ++p) {
        int dr = rl + p * 32;
        *(bf16x8*)(out + (long long)(d0 + dr) * D + e0 + c8) = *(bf16x8*)(&tile[dr][c8]);
    }
}

// ---------------- bvo = Wo @ bv (fp32) ----------------
__global__ __launch_bounds__(256) void bvo_kernel(
    const float* __restrict__ Wo, const float* __restrict__ bv, float* __restrict__ bvo)
{
    const int row = blockIdx.x;
    const int t = threadIdx.x;
    float4 w = *(const float4*)(Wo + (long long)row * D + t * 4);
    float4 b = *(const float4*)(bv + t * 4);
    float s = w.x*b.x + w.y*b.y + w.z*b.z + w.w*b.w;
    __shared__ float red[256];
    red[t] = s; __syncthreads();
    for (int off = 128; off > 0; off >>= 1) {
        if (t < off) red[t] += red[t + off];
        __syncthreads();
    }
    if (t == 0) bvo[row] = red[0];
}

// ---------------- Ksum[b][d] = sum_s Kt[b][d][s] (one wave per row) ----------------
__global__ __launch_bounds__(256) void kcolsum(const bf16* __restrict__ Kt,
                                               float* __restrict__ ks)
{
    const int row  = blockIdx.x * 4 + (threadIdx.x >> 6);   // 0..8191 = b*1024+d
    const int lane = threadIdx.x & 63;
    const bf16* r = Kt + (long long)row * S;
    float s = 0.0f;
    #pragma unroll
    for (int it = 0; it < 8; ++it) {
        bf16x8 v = *(const bf16x8*)(r + it * 512 + lane * 8);
        #pragma unroll
        for (int j = 0; j < 8; ++j) s += (float)v[j];
    }
    #pragma unroll
    for (int off = 32; off > 0; off >>= 1) s += __shfl_down(s, off);
    if (lane == 0) ks[row] = s;
}

// ---------------- MT[b] = part[2b] + part[2b+1], in-place into slab 2b ----------------
__global__ __launch_bounds__(256) void kv_add(bf16* __restrict__ p)
{
    const long long DD = (long long)D * D;
    const int b = blockIdx.y;
    const long long i = ((long long)blockIdx.x * 256 + threadIdx.x) * 8;
    bf16x8 u = *(const bf16x8*)(p + (2 * b) * DD + i);
    bf16x8 v = *(const bf16x8*)(p + (2 * b + 1) * DD + i);
    bf16x8 r;
    #pragma unroll
    for (int j = 0; j < 8; ++j) r[j] = (bf16)((float)u[j] + (float)v[j]);
    *(bf16x8*)(p + (2 * b) * DD + i) = r;   // same addr as u-read: race-free
}

// ---------------- R3 ring GEMM (small shapes: Wvo prep only) ----------------
template<int BM, int BN, int WM, int WN, int EPI, int OUTF32, int BIASROW>
__global__ __launch_bounds__(WM * WN * 64, 2) void gemm_bt(
    const bf16* __restrict__ A, const bf16* __restrict__ Bm,
    const float* __restrict__ bias, void* __restrict__ Cout,
    int lda, int ldb, int ldc, int K,
    long long aBatch, long long bBatch, long long cBatch)
{
    constexpr int THREADS = WM * WN * 64;
    constexpr int WROWS = BM / WM, WCOLS = BN / WN;
    constexpr int MI = WROWS / 16, NI = WCOLS / 16;
    constexpr int ABYTES = BM * 64;
    constexpr int BBYTES = BN * 64;
    constexpr int BUF = ABYTES + BBYTES;

    __shared__ unsigned char smem[4 * BUF];

    const int tid  = threadIdx.x;
    const int lane = tid & 63;
    const int wave = tid >> 6;
    const int wr   = wave / WN;
    const int wc   = wave % WN;
    const int bz   = blockIdx.z;

    const int nx  = gridDim.x;
    const int bid = blockIdx.y * nx + blockIdx.x;
    const int cpx = (nx * gridDim.y) >> 3;
    const int swz = (bid & 7) * cpx + (bid >> 3);
    const long long m0 = (long long)(swz / nx) * BM;
    const long long n0 = (long long)(swz % nx) * BN;

    const bf16* Ab = A  + bz * aBatch + m0 * lda;
    const bf16* Bb = Bm + bz * bBatch + n0 * ldb;

    f32x4 acc[MI][NI] = {};
    const int NT = K >> 5;

    auto stage = [&](int t) {
        unsigned char* dst = smem + (t & 3) * BUF;
        const long long kk = (long long)t << 5;
        #pragma unroll
        for (int j = 0; j < 2; ++j) {
            const int g  = wave * 64 + lane + j * THREADS;
            const int gs = g ^ ((g >> 3) & 3);
            const int row = gs >> 2, col = (gs & 3) * 8;
            load_lds16(Ab + (long long)row * lda + kk + col,
                       dst + (wave * 64 + j * THREADS) * 16);
        }
        #pragma unroll
        for (int j = 0; j < 2; ++j) {
            const int g  = wave * 64 + lane + j * THREADS;
            const int gs = g ^ ((g >> 3) & 3);
            const int row = gs >> 2, col = (gs & 3) * 8;
            load_lds16(Bb + (long long)row * ldb + kk + col,
                       dst + ABYTES + (wave * 64 + j * THREADS) * 16);
        }
    };

    stage(0); stage(1); stage(2);

    const int ko2 = (lane >> 4) * 16;
    const int la15 = lane & 15;

    for (int t = 0; t < NT; ++t) {
        if (t + 2 < NT)      asm volatile("s_waitcnt vmcnt(8)" ::: "memory");
        else if (t + 1 < NT) asm volatile("s_waitcnt vmcnt(4)" ::: "memory");
        else                 asm volatile("s_waitcnt vmcnt(0)" ::: "memory");
        __builtin_amdgcn_s_barrier();
        asm volatile("" ::: "memory");

        if (t + 3 < NT) stage(t + 3);

        const unsigned char* buf = smem + (t & 3) * BUF;
        bf16x8 a[MI], b[NI];
        #pragma unroll
        for (int mi = 0; mi < MI; ++mi) {
            int ad = (wr * WROWS + mi * 16 + la15) * 64 + ko2;
            ad ^= ((ad >> 7) & 3) << 4;
            a[mi] = *(const bf16x8*)(buf + ad);
        }
        #pragma unroll
        for (int ni = 0; ni < NI; ++ni) {
            int ad = (wc * WCOLS + ni * 16 + la15) * 64 + ko2;
            ad ^= ((ad >> 7) & 3) << 4;
            b[ni] = *(const bf16x8*)(buf + ABYTES + ad);
        }

        __builtin_amdgcn_s_setprio(1);
        #pragma unroll
        for (int mi = 0; mi < MI; ++mi)
            #pragma unroll
            for (int ni = 0; ni < NI; ++ni)
                acc[mi][ni] = __builtin_amdgcn_mfma_f32_16x16x32_bf16(
                    a[mi], b[ni], acc[mi][ni], 0, 0, 0);
        __builtin_amdgcn_s_setprio(0);
    }

    const int crow = (lane >> 4) * 4;
    const int ccol = lane & 15;
    #pragma unroll
    for (int ni = 0; ni < NI; ++ni) {
        const long long c = n0 + wc * WCOLS + ni * 16 + ccol;
        float bcol = 0.0f;
        if (!BIASROW && bias) bcol = bias[c];
        #pragma unroll
        for (int mi = 0; mi < MI; ++mi) {
            const long long r0 = m0 + wr * WROWS + mi * 16 + crow;
            #pragma unroll
            for (int j = 0; j < 4; ++j) {
                float v = acc[mi][ni][j];
                v += BIASROW ? bias[r0 + j] : bcol;
                if (EPI == 1) v = (v > 0.0f) ? (v + 1.0f) : __expf(v);
                const long long idx = bz * cBatch + (r0 + j) * ldc + c;
                if (OUTF32) ((float*)Cout)[idx] = v;
                else        ((bf16*)Cout)[idx]  = (bf16)v;
            }
        }
    }
}

// ---------------- 256^2 8-phase GEMM, single barrier/phase (R11) ----------------
// EPI: 1 = elu+1; 2 = elu+1 iff m0<1024; 3 = rank-1 add (v += bias[row]*ksum[col]).
// SPLITK: z = batch*SPLITK + kseg. GROUPN: 0 = A-reuse enum; 1 = B-reuse enum.
template<int EPI, int OUTF32, int BIASROW, int SPLITK, int GROUPN>
__global__ __launch_bounds__(512, 1) void gemm8p(
    const bf16* __restrict__ A, const bf16* __restrict__ Bm,
    const float* __restrict__ bias, const float* __restrict__ ksum,
    void* __restrict__ Cout,
    int lda, int ldb, int ldc, int K,
    long long aBatch, long long bBatch, long long cBatch)
{
    __shared__ unsigned char smem[131072];

    const int tid  = threadIdx.x;
    const int lane = tid & 63;
    const int wave = tid >> 6;
    const int wr   = wave >> 2;
    const int wc   = wave & 3;
    const int bz    = blockIdx.z;
    const int batch = bz / SPLITK;
    const int kseg  = bz % SPLITK;

    const int nx  = gridDim.x;
    const int ny  = gridDim.y;
    const int bid = blockIdx.y * nx + blockIdx.x;
    const int cpx = (nx * ny) >> 3;
    const int swzb = (bid & 7) * cpx + (bid >> 3);
    long long m0, n0;
    if (GROUPN) { n0 = (long long)(swzb / ny) * 256; m0 = (long long)(swzb % ny) * 256; }
    else        { m0 = (long long)(swzb / nx) * 256; n0 = (long long)(swzb % nx) * 256; }

    const bf16* Ab = A  + batch * aBatch + m0 * lda + (long long)kseg * K;
    const bf16* Bb = Bm + batch * bBatch + n0 * ldb + (long long)kseg * K;

    const int sg = (lane & 3) ^ ((lane >> 3) & 3);
    const long long srow = wave * 32 + (lane >> 2);
    const bf16* srcA  = Ab + srow * lda + sg * 8;
    const bf16* srcA2 = srcA + 16 * (long long)lda;
    const bf16* srcB  = Bb + srow * ldb + sg * 8;
    const bf16* srcB2 = srcB + 16 * (long long)ldb;
    const int dstoff = wave * 2048;

    const int la15 = lane & 15;
    const int rsw  = (lane >> 4) ^ ((la15 >> 1) & 3);
    const int a16  = (wr * 128 + la15) * 4 + rsw;
    const int b16  = (wc * 64  + la15) * 4 + rsw;

    f32x4 acc[8][4] = {};
    const int NT = K >> 6;
    const int NI = NT >> 1;

    auto stageA = [&](int T, int kh) {
        const int reg = ((((T & 1) << 1) | kh) << 14);
        const long long kp = ((long long)T << 6) + (kh << 5);
        load_lds16(srcA  + kp, smem + reg + dstoff);
        load_lds16(srcA2 + kp, smem + reg + dstoff + 1024);
    };
    auto stageB = [&](int T, int kh) {
        const int reg = 65536 + ((((T & 1) << 1) | kh) << 14);
        const long long kp = ((long long)T << 6) + (kh << 5);
        load_lds16(srcB  + kp, smem + reg + dstoff);
        load_lds16(srcB2 + kp, smem + reg + dstoff + 1024);
    };

    stageB(0, 0); stageA(0, 0); stageB(0, 1); stageA(0, 1);
    stageB(1, 0); stageA(1, 0); stageB(1, 1);
    asm volatile("s_waitcnt vmcnt(6)" ::: "memory");

    bf16x8 bfr[4];
    for (int i = 0; i < NI; ++i) {
        const int t = 2 * i;
        const bool nl = (i + 1 < NI);
        #pragma unroll
        for (int p = 0; p < 8; ++p) {
            const int ks  = (p >> 1) & 1;
            const int ch  = p & 1;
            const int buf = p >> 2;
            const int regA = ((buf << 1) | ks) << 14;
            const int regB = 65536 + regA;

            __builtin_amdgcn_s_barrier();
            __builtin_amdgcn_sched_barrier(0);

            bf16x8 afr[4];
            if (ch == 0) {
                #pragma unroll
                for (int ni = 0; ni < 4; ++ni)
                    bfr[ni] = *(const bf16x8*)(smem + regB + (b16 + ni * 64) * 16);
            }
            #pragma unroll
            for (int m4 = 0; m4 < 4; ++m4)
                afr[m4] = *(const bf16x8*)(smem + regA + (a16 + (ch * 4 + m4) * 64) * 16);

            if      (p == 0) stageA(t + 1, 1);
            else if (p == 1) { if (t + 2 < NT) stageB(t + 2, 0); }
            else if (p == 2) { if (t + 2 < NT) stageA(t + 2, 0); }
            else if (p == 3) { if (t + 2 < NT) stageB(t + 2, 1); }
            else if (p == 4) { if (t + 2 < NT) stageA(t + 2, 1); }
            else if (p == 5) { if (t + 3 < NT) stageB(t + 3, 0); }
            else if (p == 6) { if (t + 3 < NT) stageA(t + 3, 0); }
            else             { if (t + 3 < NT) stageB(t + 3, 1); }

            if (p == 3) {
                if (nl) asm volatile("s_waitcnt vmcnt(6)" ::: "memory");
                else    asm volatile("s_waitcnt vmcnt(0)" ::: "memory");
            } else if (p == 7) {
                if (nl) asm volatile("s_waitcnt vmcnt(6)" ::: "memory");
            }

            __builtin_amdgcn_s_setprio(1);
            #pragma unroll
            for (int m4 = 0; m4 < 4; ++m4)
                #pragma unroll
                for (int ni = 0; ni < 4; ++ni)
                    acc[ch * 4 + m4][ni] = __builtin_amdgcn_mfma_f32_16x16x32_bf16(
                        afr[m4], bfr[ni], acc[ch * 4 + m4][ni], 0, 0, 0);
            __builtin_amdgcn_s_setprio(0);
        }
    }

    // ---- epilogue (all paths via LDS for contiguous stores) ----
    const bool doElu = (EPI == 1) || (EPI == 2 && m0 < 1024);
    const long long cb = (long long)bz * cBatch;
    const int crow = (lane >> 4) * 4;

    if constexpr (OUTF32 != 0) {
        float* lt = (float*)smem;
        #pragma unroll
        for (int q = 0; q < 4; ++q) {
            __builtin_amdgcn_s_barrier();
            __builtin_amdgcn_sched_barrier(0);
            if (wr == (q >> 1)) {
                #pragma unroll
                for (int m4 = 0; m4 < 4; ++m4) {
                    const int mi = (q & 1) * 4 + m4;
                    const int lrow = m4 * 16 + crow;
                    const long long r0 = m0 + q * 64 + lrow;
                    #pragma unroll
                    for (int ni = 0; ni < 4; ++ni) {
                        const int lcol = wc * 64 + ni * 16 + la15;
                        float bb = 0.0f;
                        if (!BIASROW && bias) bb = bias[n0 + lcol];
                        #pragma unroll
                        for (int j = 0; j < 4; ++j) {
                            float v = acc[mi][ni][j] + (BIASROW ? bias[r0 + j] : bb);
                            if (doElu) v = (v > 0.0f) ? (v + 1.0f) : __expf(v);
                            lt[(lrow + j) * 260 + lcol] = v;
                        }
                    }
                }
            }
            __builtin_amdgcn_s_barrier();
            #pragma unroll
            for (int it = 0; it < 8; ++it) {
                const int chk = it * 512 + tid;
                const int r   = chk >> 6;
                const int g   = chk & 63;
                float4 v = *(const float4*)(lt + r * 260 + g * 4);
                *(float4*)((float*)Cout + cb + (m0 + q * 64 + r) * ldc + n0 + g * 4) = v;
            }
        }
    } else {
        bf16* lt = (bf16*)smem;
        #pragma unroll
        for (int half = 0; half < 2; ++half) {
            __builtin_amdgcn_s_barrier();
            __builtin_amdgcn_sched_barrier(0);
            if (wr == half) {
                #pragma unroll
                for (int mi = 0; mi < 8; ++mi) {
                    const int lrow = mi * 16 + crow;
                    const long long r0 = m0 + half * 128 + lrow;
                    #pragma unroll
                    for (int ni = 0; ni < 4; ++ni) {
                        const int lcol = wc * 64 + ni * 16 + la15;
                        float bb = 0.0f;
                        if (!BIASROW && bias) bb = bias[n0 + lcol];
                        float ksv = 0.0f;
                        if (EPI == 3 && ksum)
                            ksv = ksum[(long long)batch * D + n0 + lcol];
                        #pragma unroll
                        for (int j = 0; j < 4; ++j) {
                            float v;
                            if (EPI == 3) {
                                v = acc[mi][ni][j] + bias[r0 + j] * ksv;
                            } else {
                                v = acc[mi][ni][j] + (BIASROW ? bias[r0 + j] : bb);
                                if (doElu) v = (v > 0.0f) ? (v + 1.0f) : __expf(v);
                            }
                            lt[(lrow + j) * 264 + lcol] = (bf16)v;
                        }
                    }
                }
            }
            __builtin_amdgcn_s_barrier();
            #pragma unroll
            for (int it = 0; it < 8; ++it) {
                const int chk = it * 512 + tid;
                const int m   = chk >> 5;
                const int nof = (chk & 31) * 8;
                bf16x8 v = *(const bf16x8*)(lt + m * 264 + nof);
                *(bf16x8*)((bf16*)Cout + cb + (m0 + half * 128 + m) * ldc + n0 + nof) = v;
            }
        }
    }
}

// ---------------- launch ----------------
extern "C" void kernel_launch(void* const* d_in, const int* in_sizes, int n_in,
                              void* d_out, int out_size, void* d_ws, size_t ws_size,
                              hipStream_t stream)
{
    const float* x  = (const float*)d_in[0];
    const float* Wq = (const float*)d_in[1];
    const float* bq = (const float*)d_in[2];
    const float* Wk = (const float*)d_in[3];
    const float* bk = (const float*)d_in[4];
    const float* Wv = (const float*)d_in[5];
    const float* bv = (const float*)d_in[6];
    const float* Wo = (const float*)d_in[7];
    const float* bo = (const float*)d_in[8];
    float* out = (float*)d_out;

    // ws layout (152 MiB):
    //  [0,64M)     xbp [b][s][f]
    //  [64M,96M)   M partials (16 x 2MB slabs) -> MT in even slabs -> then Qb
    //  [96M,96M+32K)  Ksum (fp32 8192)   [+32K,+36K) bvo  (both die before Qb)
    //  [64M,128M)  Qb (written after KVo-gemm; clobbers partials/Ksum/bvo)
    //  [128M,144M) wvT temp (2MB, dead early) -> then KVo (16MB)
    //  [144M,152M) wqb | wob | wkb | Wvo  (2MB each)
    // d_out scratch: Kt [0,64M), xT [64M,128M) — both dead before final write.
    char* ws = (char*)d_ws;
    if (ws_size < (size_t)159383552) return;
    bf16*  xbp  = (bf16*)(ws + 0);
    bf16*  part = (bf16*)(ws + 67108864);
    bf16*  Qb   = (bf16*)(ws + 67108864);
    float* ks   = (float*)(ws + 100663296);
    float* bvo  = (float*)(ws + 100663296 + 32768);
    bf16*  wvT  = (bf16*)(ws + 134217728);
    bf16*  KVo  = (bf16*)(ws + 134217728);
    bf16*  wqb  = (bf16*)(ws + 150994944);
    bf16*  wob  = wqb + 1048576;
    bf16*  wkb  = wob + 1048576;
    bf16*  Wvo  = wkb + 1048576;
    bf16*  Kt   = (bf16*)d_out;            // [b][d][s]
    bf16*  xT   = Kt + NELEM;              // [b][f][s]

    const long long SD = (long long)S * D;
    const long long DD = (long long)D * D;

    // 1) converts + folded-weight prep
    cvt_permute<<<8192, 256, 0, stream>>>(x, xbp);
    cvt_w3<<<dim3(1024, 3), 256, 0, stream>>>(Wq, Wo, Wk, wqb, wob, wkb);
    cvt_transpose_1024<<<dim3(16, 16), 256, 0, stream>>>(Wv, wvT);
    bvo_kernel<<<1024, 256, 0, stream>>>(Wo, bv, bvo);
    transpose_bsd_bds<<<dim3(64, 16, 8), 256, 0, stream>>>(xbp, xT);

    // 2) Wvo[e'][f] = sum_ve Wo[e'][ve] Wv[ve][f]  (A=wob, B=wvT)
    gemm_bt<128, 128, 2, 2, 0, 0, 0><<<dim3(8, 8, 1), 256, 0, stream>>>(
        wob, wvT, nullptr, Wvo, D, D, D, D, 0, 0, 0);

    // 3) K projection: Kt[b][d][s] = elu(Wk xbp_b^T + bk)+1
    gemm8p<1, 0, 1, 1, 1><<<dim3(16, 4, 8), 512, 0, stream>>>(
        wkb, xbp, bk, nullptr, Kt, D, D, S, D, 0, SD, SD);

    // 4) Ksum[b][d] = sum_s Kt[b][d][s]
    kcolsum<<<2048, 256, 0, stream>>>(Kt, ks);

    // 5) M partials: part[2b+h][d][f] = sum_{s half h} Kt[b][d][s] xT[b][f][s]
    gemm8p<0, 0, 0, 2, 0><<<dim3(4, 4, 16), 512, 0, stream>>>(
        Kt, xT, nullptr, nullptr, part, S, S, D, 2048, SD, SD, DD);

    // 6) MT[b] = part[2b] + part[2b+1]  (in-place into even slabs)
    kv_add<<<dim3(512, 8), 256, 0, stream>>>(part);

    // 7) KVo[b][e'][d] = sum_f Wvo[e'][f] MT[b][d][f] + bvo[e']*Ksum[b][d]
    gemm8p<3, 0, 1, 1, 0><<<dim3(4, 4, 8), 512, 0, stream>>>(
        Wvo, part, bvo, ks, KVo, D, D, D, D, 0, 2 * DD, DD);

    // 8) Qb[b][s][d] = elu(xbp_b Wq^T + bq)+1  (clobbers partials/Ksum/bvo)
    gemm8p<1, 0, 0, 1, 0><<<dim3(4, 16, 8), 512, 0, stream>>>(
        xbp, wqb, bq, nullptr, Qb, D, D, D, D, SD, 0, SD);

    // 9) out[s][b][e'] = Qb[b] @ KVo[b]^T + bo  (fp32; C row s at b*D offset)
    gemm8p<0, 1, 0, 1, 0><<<dim3(4, 16, 8), 512, 0, stream>>>(
        Qb, KVo, bo, nullptr, out, D, D, B * D, D,
        SD, DD, (long long)D);
}

// Round 16
// 458.739 us; speedup vs baseline: 9.4079x; 1.0191x over previous
//
#include <hip/hip_runtime.h>

// LinearAttention, S=4096 B=8 D=1024.
// Algebraic form: K = elu(Wk x^T + bk)+1 (only nonlinear proj materialized);
//   MT[b][d][f] = sum_s K[s,d] x[s,f];  KVo = Wvo*MT^T + bvo (x) Ksum;
//   out = (elu(x Wq^T + bq)+1) @ KVo^T + bo.   Wvo = Wo Wv, bvo = Wo bv.
// gemm8p: 256^2, 8 phases/iter, 1 barrier/phase, vmcnt(6)@P3/P7 (R11-verified).
// R16: fused permute+transpose of x; Ksum folded into K-proj epilogue (atomics).

typedef __bf16 bf16;
typedef __attribute__((ext_vector_type(8))) __bf16 bf16x8;
typedef __attribute__((ext_vector_type(4))) __bf16 bf16x4;
typedef __attribute__((ext_vector_type(4))) float f32x4;

static constexpr int S = 4096;
static constexpr int B = 8;
static constexpr int D = 1024;
static constexpr int SB = S * B;
static constexpr long long NELEM = (long long)SB * D;

__device__ __forceinline__ void load_lds16(const bf16* g, void* l)
{
    __builtin_amdgcn_global_load_lds(
        (const __attribute__((address_space(1))) void*)g,
        (__attribute__((address_space(3))) void*)l, 16, 0, 0);
}

// ---------------- 3x weight fp32 -> bf16 convert (merged) ----------------
__global__ void cvt_w3(const float* __restrict__ w0, const float* __restrict__ w1,
                       const float* __restrict__ w2, bf16* __restrict__ o0,
                       bf16* __restrict__ o1, bf16* __restrict__ o2)
{
    const float* in;
    bf16* out;
    if (blockIdx.y == 0)      { in = w0; out = o0; }
    else if (blockIdx.y == 1) { in = w1; out = o1; }
    else                      { in = w2; out = o2; }
    int i = (blockIdx.x * blockDim.x + threadIdx.x) * 4;
    float4 v = *(const float4*)(in + i);
    bf16x4 o;
    o[0] = (bf16)v.x; o[1] = (bf16)v.y; o[2] = (bf16)v.z; o[3] = (bf16)v.w;
    *(bf16x4*)(out + i) = o;
}

// ---- x [S][B][D] fp32 -> xbp [B][S][D] bf16 AND xT [B][D][S] bf16 (one pass) ----
__global__ __launch_bounds__(256) void cvt_permute_both(
    const float* __restrict__ in, bf16* __restrict__ xbp, bf16* __restrict__ xT)
{
    __shared__ bf16 tile[64 * 72];   // tile[f][s]
    const int b  = blockIdx.z;
    const int s0 = blockIdx.x * 64;
    const int f0 = blockIdx.y * 64;
    const int t  = threadIdx.x;
    const int rl = t >> 3;           // 0..31
    const int c8 = (t & 7) * 8;      // 0..56
    const long long SD = (long long)S * D;

    #pragma unroll
    for (int p = 0; p < 2; ++p) {
        const int r = rl + p * 32;   // s offset in tile
        const float* src = in + (long long)(s0 + r) * (B * D) + b * D + f0 + c8;
        float4 v0 = *(const float4*)(src);
        float4 v1 = *(const float4*)(src + 4);
        bf16x8 o;
        o[0] = (bf16)v0.x; o[1] = (bf16)v0.y; o[2] = (bf16)v0.z; o[3] = (bf16)v0.w;
        o[4] = (bf16)v1.x; o[5] = (bf16)v1.y; o[6] = (bf16)v1.z; o[7] = (bf16)v1.w;
        *(bf16x8*)(xbp + b * SD + (long long)(s0 + r) * D + f0 + c8) = o;
        #pragma unroll
        for (int j = 0; j < 8; ++j)
            tile[(c8 + j) * 72 + r] = o[j];
    }
    __syncthreads();
    #pragma unroll
    for (int p = 0; p < 2; ++p) {
        const int fr = rl + p * 32;  // f offset in tile
        *(bf16x8*)(xT + b * SD + (long long)(f0 + fr) * S + s0 + c8) =
            *(const bf16x8*)(&tile[fr * 72 + c8]);
    }
}

// ---------------- Wv (fp32 [e][d]) -> WvT (bf16 [d][e]) ----------------
__global__ __launch_bounds__(256) void cvt_transpose_1024(
    const float* __restrict__ in, bf16* __restrict__ out)
{
    __shared__ bf16 tile[64][72];
    const int e0 = blockIdx.y * 64;
    const int d0 = blockIdx.x * 64;
    const int t  = threadIdx.x;
    const int rl = t >> 3;
    const int c8 = (t & 7) * 8;
    #pragma unroll
    for (int p = 0; p < 2; ++p) {
        int r = rl + p * 32;
        float4 v0 = *(const float4*)(in + (long long)(e0 + r) * D + d0 + c8);
        float4 v1 = *(const float4*)(in + (long long)(e0 + r) * D + d0 + c8 + 4);
        tile[c8+0][r] = (bf16)v0.x; tile[c8+1][r] = (bf16)v0.y;
        tile[c8+2][r] = (bf16)v0.z; tile[c8+3][r] = (bf16)v0.w;
        tile[c8+4][r] = (bf16)v1.x; tile[c8+5][r] = (bf16)v1.y;
        tile[c8+6][r] = (bf16)v1.z; tile[c8+7][r] = (bf16)v1.w;
    }
    __syncthreads();
    #pragma unroll
    for (int p = 0; p < 2; ++p) {
        int dr = rl + p * 32;
        *(bf16x8*)(out + (long long)(d0 + dr) * D + e0 + c8) = *(bf16x8*)(&tile[dr][c8]);
    }
}

// ---------------- bvo = Wo @ bv (fp32) ----------------
__global__ __launch_bounds__(256) void bvo_kernel(
    const float* __restrict__ Wo, const float* __restrict__ bv, float* __restrict__ bvo)
{
    const int row = blockIdx.x;
    const int t = threadIdx.x;
    float4 w = *(const float4*)(Wo + (long long)row * D + t * 4);
    float4 b = *(const float4*)(bv + t * 4);
    float s = w.x*b.x + w.y*b.y + w.z*b.z + w.w*b.w;
    __shared__ float red[256];
    red[t] = s; __syncthreads();
    for (int off = 128; off > 0; off >>= 1) {
        if (t < off) red[t] += red[t + off];
        __syncthreads();
    }
    if (t == 0) bvo[row] = red[0];
}

// ---------------- MT[b] = part[2b] + part[2b+1], in-place into slab 2b ----------------
__global__ __launch_bounds__(256) void kv_add(bf16* __restrict__ p)
{
    const long long DD = (long long)D * D;
    const int b = blockIdx.y;
    const long long i = ((long long)blockIdx.x * 256 + threadIdx.x) * 8;
    bf16x8 u = *(const bf16x8*)(p + (2 * b) * DD + i);
    bf16x8 v = *(const bf16x8*)(p + (2 * b + 1) * DD + i);
    bf16x8 r;
    #pragma unroll
    for (int j = 0; j < 8; ++j) r[j] = (bf16)((float)u[j] + (float)v[j]);
    *(bf16x8*)(p + (2 * b) * DD + i) = r;   // same addr as u-read: race-free
}

// ---------------- R3 ring GEMM (small shapes: Wvo prep only) ----------------
template<int BM, int BN, int WM, int WN, int EPI, int OUTF32, int BIASROW>
__global__ __launch_bounds__(WM * WN * 64, 2) void gemm_bt(
    const bf16* __restrict__ A, const bf16* __restrict__ Bm,
    const float* __restrict__ bias, void* __restrict__ Cout,
    int lda, int ldb, int ldc, int K,
    long long aBatch, long long bBatch, long long cBatch)
{
    constexpr int THREADS = WM * WN * 64;
    constexpr int WROWS = BM / WM, WCOLS = BN / WN;
    constexpr int MI = WROWS / 16, NI = WCOLS / 16;
    constexpr int ABYTES = BM * 64;
    constexpr int BBYTES = BN * 64;
    constexpr int BUF = ABYTES + BBYTES;

    __shared__ unsigned char smem[4 * BUF];

    const int tid  = threadIdx.x;
    const int lane = tid & 63;
    const int wave = tid >> 6;
    const int wr   = wave / WN;
    const int wc   = wave % WN;
    const int bz   = blockIdx.z;

    const int nx  = gridDim.x;
    const int bid = blockIdx.y * nx + blockIdx.x;
    const int cpx = (nx * gridDim.y) >> 3;
    const int swz = (bid & 7) * cpx + (bid >> 3);
    const long long m0 = (long long)(swz / nx) * BM;
    const long long n0 = (long long)(swz % nx) * BN;

    const bf16* Ab = A  + bz * aBatch + m0 * lda;
    const bf16* Bb = Bm + bz * bBatch + n0 * ldb;

    f32x4 acc[MI][NI] = {};
    const int NT = K >> 5;

    auto stage = [&](int t) {
        unsigned char* dst = smem + (t & 3) * BUF;
        const long long kk = (long long)t << 5;
        #pragma unroll
        for (int j = 0; j < 2; ++j) {
            const int g  = wave * 64 + lane + j * THREADS;
            const int gs = g ^ ((g >> 3) & 3);
            const int row = gs >> 2, col = (gs & 3) * 8;
            load_lds16(Ab + (long long)row * lda + kk + col,
                       dst + (wave * 64 + j * THREADS) * 16);
        }
        #pragma unroll
        for (int j = 0; j < 2; ++j) {
            const int g  = wave * 64 + lane + j * THREADS;
            const int gs = g ^ ((g >> 3) & 3);
            const int row = gs >> 2, col = (gs & 3) * 8;
            load_lds16(Bb + (long long)row * ldb + kk + col,
                       dst + ABYTES + (wave * 64 + j * THREADS) * 16);
        }
    };

    stage(0); stage(1); stage(2);

    const int ko2 = (lane >> 4) * 16;
    const int la15 = lane & 15;

    for (int t = 0; t < NT; ++t) {
        if (t + 2 < NT)      asm volatile("s_waitcnt vmcnt(8)" ::: "memory");
        else if (t + 1 < NT) asm volatile("s_waitcnt vmcnt(4)" ::: "memory");
        else                 asm volatile("s_waitcnt vmcnt(0)" ::: "memory");
        __builtin_amdgcn_s_barrier();
        asm volatile("" ::: "memory");

        if (t + 3 < NT) stage(t + 3);

        const unsigned char* buf = smem + (t & 3) * BUF;
        bf16x8 a[MI], b[NI];
        #pragma unroll
        for (int mi = 0; mi < MI; ++mi) {
            int ad = (wr * WROWS + mi * 16 + la15) * 64 + ko2;
            ad ^= ((ad >> 7) & 3) << 4;
            a[mi] = *(const bf16x8*)(buf + ad);
        }
        #pragma unroll
        for (int ni = 0; ni < NI; ++ni) {
            int ad = (wc * WCOLS + ni * 16 + la15) * 64 + ko2;
            ad ^= ((ad >> 7) & 3) << 4;
            b[ni] = *(const bf16x8*)(buf + ABYTES + ad);
        }

        __builtin_amdgcn_s_setprio(1);
        #pragma unroll
        for (int mi = 0; mi < MI; ++mi)
            #pragma unroll
            for (int ni = 0; ni < NI; ++ni)
                acc[mi][ni] = __builtin_amdgcn_mfma_f32_16x16x32_bf16(
                    a[mi], b[ni], acc[mi][ni], 0, 0, 0);
        __builtin_amdgcn_s_setprio(0);
    }

    const int crow = (lane >> 4) * 4;
    const int ccol = lane & 15;
    #pragma unroll
    for (int ni = 0; ni < NI; ++ni) {
        const long long c = n0 + wc * WCOLS + ni * 16 + ccol;
        float bcol = 0.0f;
        if (!BIASROW && bias) bcol = bias[c];
        #pragma unroll
        for (int mi = 0; mi < MI; ++mi) {
            const long long r0 = m0 + wr * WROWS + mi * 16 + crow;
            #pragma unroll
            for (int j = 0; j < 4; ++j) {
                float v = acc[mi][ni][j];
                v += BIASROW ? bias[r0 + j] : bcol;
                if (EPI == 1) v = (v > 0.0f) ? (v + 1.0f) : __expf(v);
                const long long idx = bz * cBatch + (r0 + j) * ldc + c;
                if (OUTF32) ((float*)Cout)[idx] = v;
                else        ((bf16*)Cout)[idx]  = (bf16)v;
            }
        }
    }
}

// ---------------- 256^2 8-phase GEMM, single barrier/phase (R11) ----------------
// EPI: 1 = elu+1; 2 = elu+1 iff m0<1024; 3 = rank-1 add (v += bias[row]*ksum[col]);
//      4 = elu+1 AND atomic row-sum into ksum[batch*D + row] (K-projection).
// SPLITK: z = batch*SPLITK + kseg. GROUPN: 0 = A-reuse enum; 1 = B-reuse enum.
template<int EPI, int OUTF32, int BIASROW, int SPLITK, int GROUPN>
__global__ __launch_bounds__(512, 1) void gemm8p(
    const bf16* __restrict__ A, const bf16* __restrict__ Bm,
    const float* __restrict__ bias, float* __restrict__ ksum,
    void* __restrict__ Cout,
    int lda, int ldb, int ldc, int K,
    long long aBatch, long long bBatch, long long cBatch)
{
    __shared__ unsigned char smem[131072];

    const int tid  = threadIdx.x;
    const int lane = tid & 63;
    const int wave = tid >> 6;
    const int wr   = wave >> 2;
    const int wc   = wave & 3;
    const int bz    = blockIdx.z;
    const int batch = bz / SPLITK;
    const int kseg  = bz % SPLITK;

    const int nx  = gridDim.x;
    const int ny  = gridDim.y;
    const int bid = blockIdx.y * nx + blockIdx.x;
    const int cpx = (nx * ny) >> 3;
    const int swzb = (bid & 7) * cpx + (bid >> 3);
    long long m0, n0;
    if (GROUPN) { n0 = (long long)(swzb / ny) * 256; m0 = (long long)(swzb % ny) * 256; }
    else        { m0 = (long long)(swzb / nx) * 256; n0 = (long long)(swzb % nx) * 256; }

    const bf16* Ab = A  + batch * aBatch + m0 * lda + (long long)kseg * K;
    const bf16* Bb = Bm + batch * bBatch + n0 * ldb + (long long)kseg * K;

    const int sg = (lane & 3) ^ ((lane >> 3) & 3);
    const long long srow = wave * 32 + (lane >> 2);
    const bf16* srcA  = Ab + srow * lda + sg * 8;
    const bf16* srcA2 = srcA + 16 * (long long)lda;
    const bf16* srcB  = Bb + srow * ldb + sg * 8;
    const bf16* srcB2 = srcB + 16 * (long long)ldb;
    const int dstoff = wave * 2048;

    const int la15 = lane & 15;
    const int rsw  = (lane >> 4) ^ ((la15 >> 1) & 3);
    const int a16  = (wr * 128 + la15) * 4 + rsw;
    const int b16  = (wc * 64  + la15) * 4 + rsw;

    f32x4 acc[8][4] = {};
    const int NT = K >> 6;
    const int NI = NT >> 1;

    auto stageA = [&](int T, int kh) {
        const int reg = ((((T & 1) << 1) | kh) << 14);
        const long long kp = ((long long)T << 6) + (kh << 5);
        load_lds16(srcA  + kp, smem + reg + dstoff);
        load_lds16(srcA2 + kp, smem + reg + dstoff + 1024);
    };
    auto stageB = [&](int T, int kh) {
        const int reg = 65536 + ((((T & 1) << 1) | kh) << 14);
        const long long kp = ((long long)T << 6) + (kh << 5);
        load_lds16(srcB  + kp, smem + reg + dstoff);
        load_lds16(srcB2 + kp, smem + reg + dstoff + 1024);
    };

    stageB(0, 0); stageA(0, 0); stageB(0, 1); stageA(0, 1);
    stageB(1, 0); stageA(1, 0); stageB(1, 1);
    asm volatile("s_waitcnt vmcnt(6)" ::: "memory");

    bf16x8 bfr[4];
    for (int i = 0; i < NI; ++i) {
        const int t = 2 * i;
        const bool nl = (i + 1 < NI);
        #pragma unroll
        for (int p = 0; p < 8; ++p) {
            const int ks  = (p >> 1) & 1;
            const int ch  = p & 1;
            const int buf = p >> 2;
            const int regA = ((buf << 1) | ks) << 14;
            const int regB = 65536 + regA;

            __builtin_amdgcn_s_barrier();
            __builtin_amdgcn_sched_barrier(0);

            bf16x8 afr[4];
            if (ch == 0) {
                #pragma unroll
                for (int ni = 0; ni < 4; ++ni)
                    bfr[ni] = *(const bf16x8*)(smem + regB + (b16 + ni * 64) * 16);
            }
            #pragma unroll
            for (int m4 = 0; m4 < 4; ++m4)
                afr[m4] = *(const bf16x8*)(smem + regA + (a16 + (ch * 4 + m4) * 64) * 16);

            if      (p == 0) stageA(t + 1, 1);
            else if (p == 1) { if (t + 2 < NT) stageB(t + 2, 0); }
            else if (p == 2) { if (t + 2 < NT) stageA(t + 2, 0); }
            else if (p == 3) { if (t + 2 < NT) stageB(t + 2, 1); }
            else if (p == 4) { if (t + 2 < NT) stageA(t + 2, 1); }
            else if (p == 5) { if (t + 3 < NT) stageB(t + 3, 0); }
            else if (p == 6) { if (t + 3 < NT) stageA(t + 3, 0); }
            else             { if (t + 3 < NT) stageB(t + 3, 1); }

            if (p == 3) {
                if (nl) asm volatile("s_waitcnt vmcnt(6)" ::: "memory");
                else    asm volatile("s_waitcnt vmcnt(0)" ::: "memory");
            } else if (p == 7) {
                if (nl) asm volatile("s_waitcnt vmcnt(6)" ::: "memory");
            }

            __builtin_amdgcn_s_setprio(1);
            #pragma unroll
            for (int m4 = 0; m4 < 4; ++m4)
                #pragma unroll
                for (int ni = 0; ni < 4; ++ni)
                    acc[ch * 4 + m4][ni] = __builtin_amdgcn_mfma_f32_16x16x32_bf16(
                        afr[m4], bfr[ni], acc[ch * 4 + m4][ni], 0, 0, 0);
            __builtin_amdgcn_s_setprio(0);
        }
    }

    // ---- epilogue (all paths via LDS for contiguous stores) ----
    const bool doElu = (EPI == 1) || (EPI == 4) || (EPI == 2 && m0 < 1024);
    const long long cb = (long long)bz * cBatch;
    const int crow = (lane >> 4) * 4;

    if constexpr (OUTF32 != 0) {
        float* lt = (float*)smem;
        #pragma unroll
        for (int q = 0; q < 4; ++q) {
            __builtin_amdgcn_s_barrier();
            __builtin_amdgcn_sched_barrier(0);
            if (wr == (q >> 1)) {
                #pragma unroll
                for (int m4 = 0; m4 < 4; ++m4) {
                    const int mi = (q & 1) * 4 + m4;
                    const int lrow = m4 * 16 + crow;
                    const long long r0 = m0 + q * 64 + lrow;
                    #pragma unroll
                    for (int ni = 0; ni < 4; ++ni) {
                        const int lcol = wc * 64 + ni * 16 + la15;
                        float bb = 0.0f;
                        if (!BIASROW && bias) bb = bias[n0 + lcol];
                        #pragma unroll
                        for (int j = 0; j < 4; ++j) {
                            float v = acc[mi][ni][j] + (BIASROW ? bias[r0 + j] : bb);
                            if (doElu) v = (v > 0.0f) ? (v + 1.0f) : __expf(v);
                            lt[(lrow + j) * 260 + lcol] = v;
                        }
                    }
                }
            }
            __builtin_amdgcn_s_barrier();
            #pragma unroll
            for (int it = 0; it < 8; ++it) {
                const int chk = it * 512 + tid;
                const int r   = chk >> 6;
                const int g   = chk & 63;
                float4 v = *(const float4*)(lt + r * 260 + g * 4);
                *(float4*)((float*)Cout + cb + (m0 + q * 64 + r) * ldc + n0 + g * 4) = v;
            }
        }
    } else {
        bf16* lt = (bf16*)smem;
        #pragma unroll
        for (int half = 0; half < 2; ++half) {
            __builtin_amdgcn_s_barrier();
            __builtin_amdgcn_sched_barrier(0);
            if (wr == half) {
                #pragma unroll
                for (int mi = 0; mi < 8; ++mi) {
                    const int lrow = mi * 16 + crow;
                    const long long r0 = m0 + half * 128 + lrow;
                    #pragma unroll
                    for (int ni = 0; ni < 4; ++ni) {
                        const int lcol = wc * 64 + ni * 16 + la15;
                        float bb = 0.0f;
                        if (!BIASROW && bias) bb = bias[n0 + lcol];
                        float ksv = 0.0f;
                        if (EPI == 3 && ksum)
                            ksv = ksum[(long long)batch * D + n0 + lcol];
                        #pragma unroll
                        for (int j = 0; j < 4; ++j) {
                            float v;
                            if (EPI == 3) {
                                v = acc[mi][ni][j] + bias[r0 + j] * ksv;
                            } else {
                                v = acc[mi][ni][j] + (BIASROW ? bias[r0 + j] : bb);
                                if (doElu) v = (v > 0.0f) ? (v + 1.0f) : __expf(v);
                            }
                            lt[(lrow + j) * 264 + lcol] = (bf16)v;
                        }
                    }
                }
            }
            __builtin_amdgcn_s_barrier();
            #pragma unroll
            for (int it = 0; it < 8; ++it) {
                const int chk = it * 512 + tid;
                const int m   = chk >> 5;
                const int nof = (chk & 31) * 8;
                bf16x8 v = *(const bf16x8*)(lt + m * 264 + nof);
                *(bf16x8*)((bf16*)Cout + cb + (m0 + half * 128 + m) * ldc + n0 + nof) = v;
            }
            if constexpr (EPI == 4) {
                // Ksum: per-row (d) partial sums of this half-tile's 256 cols (s)
                const int row = tid >> 2;             // 0..127
                const int seg = (tid & 3) * 66;       // 66*4 = 264 = row stride
                const bf16* rp = lt + row * 264 + (tid & 3) * 64;
                float s = 0.0f;
                #pragma unroll
                for (int e8 = 0; e8 < 8; ++e8) {
                    bf16x8 v = *(const bf16x8*)(rp + e8 * 8);
                    #pragma unroll
                    for (int j = 0; j < 8; ++j) s += (float)v[j];
                }
                (void)seg;
                s += __shfl_down(s, 2);
                s += __shfl_down(s, 1);
                if ((tid & 3) == 0)
                    atomicAdd(ksum + (long long)batch * D + m0 + half * 128 + row, s);
            }
        }
    }
}

// ---------------- launch ----------------
extern "C" void kernel_launch(void* const* d_in, const int* in_sizes, int n_in,
                              void* d_out, int out_size, void* d_ws, size_t ws_size,
                              hipStream_t stream)
{
    const float* x  = (const float*)d_in[0];
    const float* Wq = (const float*)d_in[1];
    const float* bq = (const float*)d_in[2];
    const float* Wk = (const float*)d_in[3];
    const float* bk = (const float*)d_in[4];
    const float* Wv = (const float*)d_in[5];
    const float* bv = (const float*)d_in[6];
    const float* Wo = (const float*)d_in[7];
    const float* bo = (const float*)d_in[8];
    float* out = (float*)d_out;

    // ws layout (152 MiB):
    //  [0,64M)     xbp [b][s][f]
    //  [64M,96M)   M partials (16 x 2MB slabs) -> MT in even slabs -> then Qb
    //  [96M,96M+32K)  Ksum (fp32 8192)   [+32K,+36K) bvo  (both die before Qb)
    //  [64M,128M)  Qb (written after KVo-gemm; clobbers partials/Ksum/bvo)
    //  [128M,144M) wvT temp (2MB, dead early) -> then KVo (16MB)
    //  [144M,152M) wqb | wob | wkb | Wvo  (2MB each)
    // d_out scratch: Kt [0,64M), xT [64M,128M) — both dead before final write.
    char* ws = (char*)d_ws;
    if (ws_size < (size_t)159383552) return;
    bf16*  xbp  = (bf16*)(ws + 0);
    bf16*  part = (bf16*)(ws + 67108864);
    bf16*  Qb   = (bf16*)(ws + 67108864);
    float* ks   = (float*)(ws + 100663296);
    float* bvo  = (float*)(ws + 100663296 + 32768);
    bf16*  wvT  = (bf16*)(ws + 134217728);
    bf16*  KVo  = (bf16*)(ws + 134217728);
    bf16*  wqb  = (bf16*)(ws + 150994944);
    bf16*  wob  = wqb + 1048576;
    bf16*  wkb  = wob + 1048576;
    bf16*  Wvo  = wkb + 1048576;
    bf16*  Kt   = (bf16*)d_out;            // [b][d][s]
    bf16*  xT   = Kt + NELEM;              // [b][f][s]

    const long long SD = (long long)S * D;
    const long long DD = (long long)D * D;

    // 1) converts + folded-weight prep (x permute + transpose fused, one pass)
    cvt_permute_both<<<dim3(64, 16, 8), 256, 0, stream>>>(x, xbp, xT);
    cvt_w3<<<dim3(1024, 3), 256, 0, stream>>>(Wq, Wo, Wk, wqb, wob, wkb);
    cvt_transpose_1024<<<dim3(16, 16), 256, 0, stream>>>(Wv, wvT);
    bvo_kernel<<<1024, 256, 0, stream>>>(Wo, bv, bvo);
    hipMemsetAsync(ks, 0, B * D * sizeof(float), stream);

    // 2) Wvo[e'][f] = sum_ve Wo[e'][ve] Wv[ve][f]  (A=wob, B=wvT)
    gemm_bt<128, 128, 2, 2, 0, 0, 0><<<dim3(8, 8, 1), 256, 0, stream>>>(
        wob, wvT, nullptr, Wvo, D, D, D, D, 0, 0, 0);

    // 3) K projection + fused Ksum: Kt[b][d][s] = elu(Wk xbp_b^T + bk)+1,
    //    ks[b][d] += row sums (atomic, 16 tiles contribute per row)
    gemm8p<4, 0, 1, 1, 1><<<dim3(16, 4, 8), 512, 0, stream>>>(
        wkb, xbp, bk, ks, Kt, D, D, S, D, 0, SD, SD);

    // 4) M partials: part[2b+h][d][f] = sum_{s half h} Kt[b][d][s] xT[b][f][s]
    gemm8p<0, 0, 0, 2, 0><<<dim3(4, 4, 16), 512, 0, stream>>>(
        Kt, xT, nullptr, nullptr, part, S, S, D, 2048, SD, SD, DD);

    // 5) MT[b] = part[2b] + part[2b+1]  (in-place into even slabs)
    kv_add<<<dim3(512, 8), 256, 0, stream>>>(part);

    // 6) KVo[b][e'][d] = sum_f Wvo[e'][f] MT[b][d][f] + bvo[e']*Ksum[b][d]
    gemm8p<3, 0, 1, 1, 0><<<dim3(4, 4, 8), 512, 0, stream>>>(
        Wvo, part, bvo, ks, KVo, D, D, D, D, 0, 2 * DD, DD);

    // 7) Qb[b][s][d] = elu(xbp_b Wq^T + bq)+1  (clobbers partials/Ksum/bvo)
    gemm8p<1, 0, 0, 1, 0><<<dim3(4, 16, 8), 512, 0, stream>>>(
        xbp, wqb, bq, nullptr, Qb, D, D, D, D, SD, 0, SD);

    // 8) out[s][b][e'] = Qb[b] @ KVo[b]^T + bo  (fp32; C row s at b*D offset)
    gemm8p<0, 1, 0, 1, 0><<<dim3(4, 16, 8), 512, 0, stream>>>(
        Qb, KVo, bo, nullptr, out, D, D, B * D, D,
        SD, DD, (long long)D);
}

// Round 17
// 457.348 us; speedup vs baseline: 9.4365x; 1.0030x over previous
//
#include <hip/hip_runtime.h>

// LinearAttention, S=4096 B=8 D=1024.
// Algebraic form: K = elu(Wk x^T + bk)+1 (only nonlinear proj materialized);
//   MT[b][d][f] = sum_s K[s,d] x[s,f];  KVo = Wvo*MT^T + bvo (x) Ksum;
//   out = (elu(x Wq^T + bq)+1) @ KVo^T + bo.   Wvo = Wo Wv, bvo = Wo bv.
// gemm8p: 256^2, 8 phases/iter, 1 barrier/phase, vmcnt(6)@P3/P7 (R11-verified).
// R17: transpose LDS tile stride 72 -> 66 (16-way bank conflict -> 4-way).

typedef __bf16 bf16;
typedef __attribute__((ext_vector_type(8))) __bf16 bf16x8;
typedef __attribute__((ext_vector_type(4))) __bf16 bf16x4;
typedef __attribute__((ext_vector_type(4))) float f32x4;

static constexpr int S = 4096;
static constexpr int B = 8;
static constexpr int D = 1024;
static constexpr int SB = S * B;
static constexpr long long NELEM = (long long)SB * D;
static constexpr int TP = 66;   // transpose tile row stride (bank-conflict-tuned)

__device__ __forceinline__ void load_lds16(const bf16* g, void* l)
{
    __builtin_amdgcn_global_load_lds(
        (const __attribute__((address_space(1))) void*)g,
        (__attribute__((address_space(3))) void*)l, 16, 0, 0);
}

// ---------------- 3x weight fp32 -> bf16 convert (merged) ----------------
__global__ void cvt_w3(const float* __restrict__ w0, const float* __restrict__ w1,
                       const float* __restrict__ w2, bf16* __restrict__ o0,
                       bf16* __restrict__ o1, bf16* __restrict__ o2)
{
    const float* in;
    bf16* out;
    if (blockIdx.y == 0)      { in = w0; out = o0; }
    else if (blockIdx.y == 1) { in = w1; out = o1; }
    else                      { in = w2; out = o2; }
    int i = (blockIdx.x * blockDim.x + threadIdx.x) * 4;
    float4 v = *(const float4*)(in + i);
    bf16x4 o;
    o[0] = (bf16)v.x; o[1] = (bf16)v.y; o[2] = (bf16)v.z; o[3] = (bf16)v.w;
    *(bf16x4*)(out + i) = o;
}

// ---- x [S][B][D] fp32 -> xbp [B][S][D] bf16 AND xT [B][D][S] bf16 (one pass) ----
__global__ __launch_bounds__(256) void cvt_permute_both(
    const float* __restrict__ in, bf16* __restrict__ xbp, bf16* __restrict__ xT)
{
    __shared__ bf16 tile[64 * TP];   // tile[f][s], stride TP=66
    const int b  = blockIdx.z;
    const int s0 = blockIdx.x * 64;
    const int f0 = blockIdx.y * 64;
    const int t  = threadIdx.x;
    const int rl = t >> 3;           // 0..31
    const int c8 = (t & 7) * 8;      // 0..56
    const long long SD = (long long)S * D;

    #pragma unroll
    for (int p = 0; p < 2; ++p) {
        const int r = rl + p * 32;   // s offset in tile
        const float* src = in + (long long)(s0 + r) * (B * D) + b * D + f0 + c8;
        float4 v0 = *(const float4*)(src);
        float4 v1 = *(const float4*)(src + 4);
        bf16x8 o;
        o[0] = (bf16)v0.x; o[1] = (bf16)v0.y; o[2] = (bf16)v0.z; o[3] = (bf16)v0.w;
        o[4] = (bf16)v1.x; o[5] = (bf16)v1.y; o[6] = (bf16)v1.z; o[7] = (bf16)v1.w;
        *(bf16x8*)(xbp + b * SD + (long long)(s0 + r) * D + f0 + c8) = o;
        #pragma unroll
        for (int j = 0; j < 8; ++j)
            tile[(c8 + j) * TP + r] = o[j];
    }
    __syncthreads();
    #pragma unroll
    for (int p = 0; p < 2; ++p) {
        const int fr = rl + p * 32;  // f offset in tile
        *(bf16x8*)(xT + b * SD + (long long)(f0 + fr) * S + s0 + c8) =
            *(const bf16x8*)(&tile[fr * TP + c8]);
    }
}

// ---------------- Wv (fp32 [e][d]) -> WvT (bf16 [d][e]) ----------------
__global__ __launch_bounds__(256) void cvt_transpose_1024(
    const float* __restrict__ in, bf16* __restrict__ out)
{
    __shared__ bf16 tile[64 * TP];   // tile[d][e], stride TP
    const int e0 = blockIdx.y * 64;
    const int d0 = blockIdx.x * 64;
    const int t  = threadIdx.x;
    const int rl = t >> 3;
    const int c8 = (t & 7) * 8;
    #pragma unroll
    for (int p = 0; p < 2; ++p) {
        int r = rl + p * 32;
        float4 v0 = *(const float4*)(in + (long long)(e0 + r) * D + d0 + c8);
        float4 v1 = *(const float4*)(in + (long long)(e0 + r) * D + d0 + c8 + 4);
        bf16x8 o;
        o[0] = (bf16)v0.x; o[1] = (bf16)v0.y; o[2] = (bf16)v0.z; o[3] = (bf16)v0.w;
        o[4] = (bf16)v1.x; o[5] = (bf16)v1.y; o[6] = (bf16)v1.z; o[7] = (bf16)v1.w;
        #pragma unroll
        for (int j = 0; j < 8; ++j)
            tile[(c8 + j) * TP + r] = o[j];
    }
    __syncthreads();
    #pragma unroll
    for (int p = 0; p < 2; ++p) {
        int dr = rl + p * 32;
        *(bf16x8*)(out + (long long)(d0 + dr) * D + e0 + c8) =
            *(const bf16x8*)(&tile[dr * TP + c8]);
    }
}

// ---------------- bvo = Wo @ bv (fp32) ----------------
__global__ __launch_bounds__(256) void bvo_kernel(
    const float* __restrict__ Wo, const float* __restrict__ bv, float* __restrict__ bvo)
{
    const int row = blockIdx.x;
    const int t = threadIdx.x;
    float4 w = *(const float4*)(Wo + (long long)row * D + t * 4);
    float4 b = *(const float4*)(bv + t * 4);
    float s = w.x*b.x + w.y*b.y + w.z*b.z + w.w*b.w;
    __shared__ float red[256];
    red[t] = s; __syncthreads();
    for (int off = 128; off > 0; off >>= 1) {
        if (t < off) red[t] += red[t + off];
        __syncthreads();
    }
    if (t == 0) bvo[row] = red[0];
}

// ---------------- MT[b] = part[2b] + part[2b+1], in-place into slab 2b ----------------
__global__ __launch_bounds__(256) void kv_add(bf16* __restrict__ p)
{
    const long long DD = (long long)D * D;
    const int b = blockIdx.y;
    const long long i = ((long long)blockIdx.x * 256 + threadIdx.x) * 8;
    bf16x8 u = *(const bf16x8*)(p + (2 * b) * DD + i);
    bf16x8 v = *(const bf16x8*)(p + (2 * b + 1) * DD + i);
    bf16x8 r;
    #pragma unroll
    for (int j = 0; j < 8; ++j) r[j] = (bf16)((float)u[j] + (float)v[j]);
    *(bf16x8*)(p + (2 * b) * DD + i) = r;   // same addr as u-read: race-free
}

// ---------------- R3 ring GEMM (small shapes: Wvo prep only) ----------------
template<int BM, int BN, int WM, int WN, int EPI, int OUTF32, int BIASROW>
__global__ __launch_bounds__(WM * WN * 64, 2) void gemm_bt(
    const bf16* __restrict__ A, const bf16* __restrict__ Bm,
    const float* __restrict__ bias, void* __restrict__ Cout,
    int lda, int ldb, int ldc, int K,
    long long aBatch, long long bBatch, long long cBatch)
{
    constexpr int THREADS = WM * WN * 64;
    constexpr int WROWS = BM / WM, WCOLS = BN / WN;
    constexpr int MI = WROWS / 16, NI = WCOLS / 16;
    constexpr int ABYTES = BM * 64;
    constexpr int BBYTES = BN * 64;
    constexpr int BUF = ABYTES + BBYTES;

    __shared__ unsigned char smem[4 * BUF];

    const int tid  = threadIdx.x;
    const int lane = tid & 63;
    const int wave = tid >> 6;
    const int wr   = wave / WN;
    const int wc   = wave % WN;
    const int bz   = blockIdx.z;

    const int nx  = gridDim.x;
    const int bid = blockIdx.y * nx + blockIdx.x;
    const int cpx = (nx * gridDim.y) >> 3;
    const int swz = (bid & 7) * cpx + (bid >> 3);
    const long long m0 = (long long)(swz / nx) * BM;
    const long long n0 = (long long)(swz % nx) * BN;

    const bf16* Ab = A  + bz * aBatch + m0 * lda;
    const bf16* Bb = Bm + bz * bBatch + n0 * ldb;

    f32x4 acc[MI][NI] = {};
    const int NT = K >> 5;

    auto stage = [&](int t) {
        unsigned char* dst = smem + (t & 3) * BUF;
        const long long kk = (long long)t << 5;
        #pragma unroll
        for (int j = 0; j < 2; ++j) {
            const int g  = wave * 64 + lane + j * THREADS;
            const int gs = g ^ ((g >> 3) & 3);
            const int row = gs >> 2, col = (gs & 3) * 8;
            load_lds16(Ab + (long long)row * lda + kk + col,
                       dst + (wave * 64 + j * THREADS) * 16);
        }
        #pragma unroll
        for (int j = 0; j < 2; ++j) {
            const int g  = wave * 64 + lane + j * THREADS;
            const int gs = g ^ ((g >> 3) & 3);
            const int row = gs >> 2, col = (gs & 3) * 8;
            load_lds16(Bb + (long long)row * ldb + kk + col,
                       dst + ABYTES + (wave * 64 + j * THREADS) * 16);
        }
    };

    stage(0); stage(1); stage(2);

    const int ko2 = (lane >> 4) * 16;
    const int la15 = lane & 15;

    for (int t = 0; t < NT; ++t) {
        if (t + 2 < NT)      asm volatile("s_waitcnt vmcnt(8)" ::: "memory");
        else if (t + 1 < NT) asm volatile("s_waitcnt vmcnt(4)" ::: "memory");
        else                 asm volatile("s_waitcnt vmcnt(0)" ::: "memory");
        __builtin_amdgcn_s_barrier();
        asm volatile("" ::: "memory");

        if (t + 3 < NT) stage(t + 3);

        const unsigned char* buf = smem + (t & 3) * BUF;
        bf16x8 a[MI], b[NI];
        #pragma unroll
        for (int mi = 0; mi < MI; ++mi) {
            int ad = (wr * WROWS + mi * 16 + la15) * 64 + ko2;
            ad ^= ((ad >> 7) & 3) << 4;
            a[mi] = *(const bf16x8*)(buf + ad);
        }
        #pragma unroll
        for (int ni = 0; ni < NI; ++ni) {
            int ad = (wc * WCOLS + ni * 16 + la15) * 64 + ko2;
            ad ^= ((ad >> 7) & 3) << 4;
            b[ni] = *(const bf16x8*)(buf + ABYTES + ad);
        }

        __builtin_amdgcn_s_setprio(1);
        #pragma unroll
        for (int mi = 0; mi < MI; ++mi)
            #pragma unroll
            for (int ni = 0; ni < NI; ++ni)
                acc[mi][ni] = __builtin_amdgcn_mfma_f32_16x16x32_bf16(
                    a[mi], b[ni], acc[mi][ni], 0, 0, 0);
        __builtin_amdgcn_s_setprio(0);
    }

    const int crow = (lane >> 4) * 4;
    const int ccol = lane & 15;
    #pragma unroll
    for (int ni = 0; ni < NI; ++ni) {
        const long long c = n0 + wc * WCOLS + ni * 16 + ccol;
        float bcol = 0.0f;
        if (!BIASROW && bias) bcol = bias[c];
        #pragma unroll
        for (int mi = 0; mi < MI; ++mi) {
            const long long r0 = m0 + wr * WROWS + mi * 16 + crow;
            #pragma unroll
            for (int j = 0; j < 4; ++j) {
                float v = acc[mi][ni][j];
                v += BIASROW ? bias[r0 + j] : bcol;
                if (EPI == 1) v = (v > 0.0f) ? (v + 1.0f) : __expf(v);
                const long long idx = bz * cBatch + (r0 + j) * ldc + c;
                if (OUTF32) ((float*)Cout)[idx] = v;
                else        ((bf16*)Cout)[idx]  = (bf16)v;
            }
        }
    }
}

// ---------------- 256^2 8-phase GEMM, single barrier/phase (R11) ----------------
// EPI: 1 = elu+1; 2 = elu+1 iff m0<1024; 3 = rank-1 add (v += bias[row]*ksum[col]);
//      4 = elu+1 AND atomic row-sum into ksum[batch*D + row] (K-projection).
// SPLITK: z = batch*SPLITK + kseg. GROUPN: 0 = A-reuse enum; 1 = B-reuse enum.
template<int EPI, int OUTF32, int BIASROW, int SPLITK, int GROUPN>
__global__ __launch_bounds__(512, 1) void gemm8p(
    const bf16* __restrict__ A, const bf16* __restrict__ Bm,
    const float* __restrict__ bias, float* __restrict__ ksum,
    void* __restrict__ Cout,
    int lda, int ldb, int ldc, int K,
    long long aBatch, long long bBatch, long long cBatch)
{
    __shared__ unsigned char smem[131072];

    const int tid  = threadIdx.x;
    const int lane = tid & 63;
    const int wave = tid >> 6;
    const int wr   = wave >> 2;
    const int wc   = wave & 3;
    const int bz    = blockIdx.z;
    const int batch = bz / SPLITK;
    const int kseg  = bz % SPLITK;

    const int nx  = gridDim.x;
    const int ny  = gridDim.y;
    const int bid = blockIdx.y * nx + blockIdx.x;
    const int cpx = (nx * ny) >> 3;
    const int swzb = (bid & 7) * cpx + (bid >> 3);
    long long m0, n0;
    if (GROUPN) { n0 = (long long)(swzb / ny) * 256; m0 = (long long)(swzb % ny) * 256; }
    else        { m0 = (long long)(swzb / nx) * 256; n0 = (long long)(swzb % nx) * 256; }

    const bf16* Ab = A  + batch * aBatch + m0 * lda + (long long)kseg * K;
    const bf16* Bb = Bm + batch * bBatch + n0 * ldb + (long long)kseg * K;

    const int sg = (lane & 3) ^ ((lane >> 3) & 3);
    const long long srow = wave * 32 + (lane >> 2);
    const bf16* srcA  = Ab + srow * lda + sg * 8;
    const bf16* srcA2 = srcA + 16 * (long long)lda;
    const bf16* srcB  = Bb + srow * ldb + sg * 8;
    const bf16* srcB2 = srcB + 16 * (long long)ldb;
    const int dstoff = wave * 2048;

    const int la15 = lane & 15;
    const int rsw  = (lane >> 4) ^ ((la15 >> 1) & 3);
    const int a16  = (wr * 128 + la15) * 4 + rsw;
    const int b16  = (wc * 64  + la15) * 4 + rsw;

    f32x4 acc[8][4] = {};
    const int NT = K >> 6;
    const int NI = NT >> 1;

    auto stageA = [&](int T, int kh) {
        const int reg = ((((T & 1) << 1) | kh) << 14);
        const long long kp = ((long long)T << 6) + (kh << 5);
        load_lds16(srcA  + kp, smem + reg + dstoff);
        load_lds16(srcA2 + kp, smem + reg + dstoff + 1024);
    };
    auto stageB = [&](int T, int kh) {
        const int reg = 65536 + ((((T & 1) << 1) | kh) << 14);
        const long long kp = ((long long)T << 6) + (kh << 5);
        load_lds16(srcB  + kp, smem + reg + dstoff);
        load_lds16(srcB2 + kp, smem + reg + dstoff + 1024);
    };

    stageB(0, 0); stageA(0, 0); stageB(0, 1); stageA(0, 1);
    stageB(1, 0); stageA(1, 0); stageB(1, 1);
    asm volatile("s_waitcnt vmcnt(6)" ::: "memory");

    bf16x8 bfr[4];
    for (int i = 0; i < NI; ++i) {
        const int t = 2 * i;
        const bool nl = (i + 1 < NI);
        #pragma unroll
        for (int p = 0; p < 8; ++p) {
            const int ks  = (p >> 1) & 1;
            const int ch  = p & 1;
            const int buf = p >> 2;
            const int regA = ((buf << 1) | ks) << 14;
            const int regB = 65536 + regA;

            __builtin_amdgcn_s_barrier();
            __builtin_amdgcn_sched_barrier(0);

            bf16x8 afr[4];
            if (ch == 0) {
                #pragma unroll
                for (int ni = 0; ni < 4; ++ni)
                    bfr[ni] = *(const bf16x8*)(smem + regB + (b16 + ni * 64) * 16);
            }
            #pragma unroll
            for (int m4 = 0; m4 < 4; ++m4)
                afr[m4] = *(const bf16x8*)(smem + regA + (a16 + (ch * 4 + m4) * 64) * 16);

            if      (p == 0) stageA(t + 1, 1);
            else if (p == 1) { if (t + 2 < NT) stageB(t + 2, 0); }
            else if (p == 2) { if (t + 2 < NT) stageA(t + 2, 0); }
            else if (p == 3) { if (t + 2 < NT) stageB(t + 2, 1); }
            else if (p == 4) { if (t + 2 < NT) stageA(t + 2, 1); }
            else if (p == 5) { if (t + 3 < NT) stageB(t + 3, 0); }
            else if (p == 6) { if (t + 3 < NT) stageA(t + 3, 0); }
            else             { if (t + 3 < NT) stageB(t + 3, 1); }

            if (p == 3) {
                if (nl) asm volatile("s_waitcnt vmcnt(6)" ::: "memory");
                else    asm volatile("s_waitcnt vmcnt(0)" ::: "memory");
            } else if (p == 7) {
                if (nl) asm volatile("s_waitcnt vmcnt(6)" ::: "memory");
            }

            __builtin_amdgcn_s_setprio(1);
            #pragma unroll
            for (int m4 = 0; m4 < 4; ++m4)
                #pragma unroll
                for (int ni = 0; ni < 4; ++ni)
                    acc[ch * 4 + m4][ni] = __builtin_amdgcn_mfma_f32_16x16x32_bf16(
                        afr[m4], bfr[ni], acc[ch * 4 + m4][ni], 0, 0, 0);
            __builtin_amdgcn_s_setprio(0);
        }
    }

    // ---- epilogue (all paths via LDS for contiguous stores) ----
    const bool doElu = (EPI == 1) || (EPI == 4) || (EPI == 2 && m0 < 1024);
    const long long cb = (long long)bz * cBatch;
    const int crow = (lane >> 4) * 4;

    if constexpr (OUTF32 != 0) {
        float* lt = (float*)smem;
        #pragma unroll
        for (int q = 0; q < 4; ++q) {
            __builtin_amdgcn_s_barrier();
            __builtin_amdgcn_sched_barrier(0);
            if (wr == (q >> 1)) {
                #pragma unroll
                for (int m4 = 0; m4 < 4; ++m4) {
                    const int mi = (q & 1) * 4 + m4;
                    const int lrow = m4 * 16 + crow;
                    const long long r0 = m0 + q * 64 + lrow;
                    #pragma unroll
                    for (int ni = 0; ni < 4; ++ni) {
                        const int lcol = wc * 64 + ni * 16 + la15;
                        float bb = 0.0f;
                        if (!BIASROW && bias) bb = bias[n0 + lcol];
                        #pragma unroll
                        for (int j = 0; j < 4; ++j) {
                            float v = acc[mi][ni][j] + (BIASROW ? bias[r0 + j] : bb);
                            if (doElu) v = (v > 0.0f) ? (v + 1.0f) : __expf(v);
                            lt[(lrow + j) * 260 + lcol] = v;
                        }
                    }
                }
            }
            __builtin_amdgcn_s_barrier();
            #pragma unroll
            for (int it = 0; it < 8; ++it) {
                const int chk = it * 512 + tid;
                const int r   = chk >> 6;
                const int g   = chk & 63;
                float4 v = *(const float4*)(lt + r * 260 + g * 4);
                *(float4*)((float*)Cout + cb + (m0 + q * 64 + r) * ldc + n0 + g * 4) = v;
            }
        }
    } else {
        bf16* lt = (bf16*)smem;
        #pragma unroll
        for (int half = 0; half < 2; ++half) {
            __builtin_amdgcn_s_barrier();
            __builtin_amdgcn_sched_barrier(0);
            if (wr == half) {
                #pragma unroll
                for (int mi = 0; mi < 8; ++mi) {
                    const int lrow = mi * 16 + crow;
                    const long long r0 = m0 + half * 128 + lrow;
                    #pragma unroll
                    for (int ni = 0; ni < 4; ++ni) {
                        const int lcol = wc * 64 + ni * 16 + la15;
                        float bb = 0.0f;
                        if (!BIASROW && bias) bb = bias[n0 + lcol];
                        float ksv = 0.0f;
                        if (EPI == 3 && ksum)
                            ksv = ksum[(long long)batch * D + n0 + lcol];
                        #pragma unroll
                        for (int j = 0; j < 4; ++j) {
                            float v;
                            if (EPI == 3) {
                                v = acc[mi][ni][j] + bias[r0 + j] * ksv;
                            } else {
                                v = acc[mi][ni][j] + (BIASROW ? bias[r0 + j] : bb);
                                if (doElu) v = (v > 0.0f) ? (v + 1.0f) : __expf(v);
                            }
                            lt[(lrow + j) * 264 + lcol] = (bf16)v;
                        }
                    }
                }
            }
            __builtin_amdgcn_s_barrier();
            #pragma unroll
            for (int it = 0; it < 8; ++it) {
                const int chk = it * 512 + tid;
                const int m   = chk >> 5;
                const int nof = (chk & 31) * 8;
                bf16x8 v = *(const bf16x8*)(lt + m * 264 + nof);
                *(bf16x8*)((bf16*)Cout + cb + (m0 + half * 128 + m) * ldc + n0 + nof) = v;
            }
            if constexpr (EPI == 4) {
                // Ksum: per-row (d) partial sums of this half-tile's 256 cols (s)
                const int row = tid >> 2;             // 0..127
                const bf16* rp = lt + row * 264 + (tid & 3) * 64;
                float s = 0.0f;
                #pragma unroll
                for (int e8 = 0; e8 < 8; ++e8) {
                    bf16x8 v = *(const bf16x8*)(rp + e8 * 8);
                    #pragma unroll
                    for (int j = 0; j < 8; ++j) s += (float)v[j];
                }
                s += __shfl_down(s, 2);
                s += __shfl_down(s, 1);
                if ((tid & 3) == 0)
                    atomicAdd(ksum + (long long)batch * D + m0 + half * 128 + row, s);
            }
        }
    }
}

// ---------------- launch ----------------
extern "C" void kernel_launch(void* const* d_in, const int* in_sizes, int n_in,
                              void* d_out, int out_size, void* d_ws, size_t ws_size,
                              hipStream_t stream)
{
    const float* x  = (const float*)d_in[0];
    const float* Wq = (const float*)d_in[1];
    const float* bq = (const float*)d_in[2];
    const float* Wk = (const float*)d_in[3];
    const float* bk = (const float*)d_in[4];
    const float* Wv = (const float*)d_in[5];
    const float* bv = (const float*)d_in[6];
    const float* Wo = (const float*)d_in[7];
    const float* bo = (const float*)d_in[8];
    float* out = (float*)d_out;

    // ws layout (152 MiB):
    //  [0,64M)     xbp [b][s][f]
    //  [64M,96M)   M partials (16 x 2MB slabs) -> MT in even slabs -> then Qb
    //  [96M,96M+32K)  Ksum (fp32 8192)   [+32K,+36K) bvo  (both die before Qb)
    //  [64M,128M)  Qb (written after KVo-gemm; clobbers partials/Ksum/bvo)
    //  [128M,144M) wvT temp (2MB, dead early) -> then KVo (16MB)
    //  [144M,152M) wqb | wob | wkb | Wvo  (2MB each)
    // d_out scratch: Kt [0,64M), xT [64M,128M) — both dead before final write.
    char* ws = (char*)d_ws;
    if (ws_size < (size_t)159383552) return;
    bf16*  xbp  = (bf16*)(ws + 0);
    bf16*  part = (bf16*)(ws + 67108864);
    bf16*  Qb   = (bf16*)(ws + 67108864);
    float* ks   = (float*)(ws + 100663296);
    float* bvo  = (float*)(ws + 100663296 + 32768);
    bf16*  wvT  = (bf16*)(ws + 134217728);
    bf16*  KVo  = (bf16*)(ws + 134217728);
    bf16*  wqb  = (bf16*)(ws + 150994944);
    bf16*  wob  = wqb + 1048576;
    bf16*  wkb  = wob + 1048576;
    bf16*  Wvo  = wkb + 1048576;
    bf16*  Kt   = (bf16*)d_out;            // [b][d][s]
    bf16*  xT   = Kt + NELEM;              // [b][f][s]

    const long long SD = (long long)S * D;
    const long long DD = (long long)D * D;

    // 1) converts + folded-weight prep (x permute + transpose fused, one pass)
    cvt_permute_both<<<dim3(64, 16, 8), 256, 0, stream>>>(x, xbp, xT);
    cvt_w3<<<dim3(1024, 3), 256, 0, stream>>>(Wq, Wo, Wk, wqb, wob, wkb);
    cvt_transpose_1024<<<dim3(16, 16), 256, 0, stream>>>(Wv, wvT);
    bvo_kernel<<<1024, 256, 0, stream>>>(Wo, bv, bvo);
    hipMemsetAsync(ks, 0, B * D * sizeof(float), stream);

    // 2) Wvo[e'][f] = sum_ve Wo[e'][ve] Wv[ve][f]  (A=wob, B=wvT)
    gemm_bt<128, 128, 2, 2, 0, 0, 0><<<dim3(8, 8, 1), 256, 0, stream>>>(
        wob, wvT, nullptr, Wvo, D, D, D, D, 0, 0, 0);

    // 3) K projection + fused Ksum: Kt[b][d][s] = elu(Wk xbp_b^T + bk)+1,
    //    ks[b][d] += row sums (atomic, 16 tiles contribute per row)
    gemm8p<4, 0, 1, 1, 1><<<dim3(16, 4, 8), 512, 0, stream>>>(
        wkb, xbp, bk, ks, Kt, D, D, S, D, 0, SD, SD);

    // 4) M partials: part[2b+h][d][f] = sum_{s half h} Kt[b][d][s] xT[b][f][s]
    gemm8p<0, 0, 0, 2, 0><<<dim3(4, 4, 16), 512, 0, stream>>>(
        Kt, xT, nullptr, nullptr, part, S, S, D, 2048, SD, SD, DD);

    // 5) MT[b] = part[2b] + part[2b+1]  (in-place into even slabs)
    kv_add<<<dim3(512, 8), 256, 0, stream>>>(part);

    // 6) KVo[b][e'][d] = sum_f Wvo[e'][f] MT[b][d][f] + bvo[e']*Ksum[b][d]
    gemm8p<3, 0, 1, 1, 0><<<dim3(4, 4, 8), 512, 0, stream>>>(
        Wvo, part, bvo, ks, KVo, D, D, D, D, 0, 2 * DD, DD);

    // 7) Qb[b][s][d] = elu(xbp_b Wq^T + bq)+1  (clobbers partials/Ksum/bvo)
    gemm8p<1, 0, 0, 1, 0><<<dim3(4, 16, 8), 512, 0, stream>>>(
        xbp, wqb, bq, nullptr, Qb, D, D, D, D, SD, 0, SD);

    // 8) out[s][b][e'] = Qb[b] @ KVo[b]^T + bo  (fp32; C row s at b*D offset)
    gemm8p<0, 1, 0, 1, 0><<<dim3(4, 16, 8), 512, 0, stream>>>(
        Qb, KVo, bo, nullptr, out, D, D, B * D, D,
        SD, DD, (long long)D);
}

// Round 18
// 457.109 us; speedup vs baseline: 9.4414x; 1.0005x over previous
//
#include <hip/hip_runtime.h>

// LinearAttention, S=4096 B=8 D=1024.
// Algebraic form: K = elu(Wk x^T + bk)+1 (only nonlinear proj materialized);
//   MT[b][d][f] = sum_s K[s,d] x[s,f];  KVo = Wvo*MT^T + bvo (x) Ksum;
//   out = (elu(x Wq^T + bq)+1) @ KVo^T + bo.   Wvo = Wo Wv, bvo = Wo bv.
// gemm8p: 256^2, 8 phases/iter, 1 barrier/phase, vmcnt(6)@P3/P7.
// R18: per-phase fence relaxed to sched_barrier(0x10F) — DS_READs may hoist
// into the previous phase's MFMA shadow; VMEM (gload_lds) stays pinned.

typedef __bf16 bf16;
typedef __attribute__((ext_vector_type(8))) __bf16 bf16x8;
typedef __attribute__((ext_vector_type(4))) __bf16 bf16x4;
typedef __attribute__((ext_vector_type(4))) float f32x4;

static constexpr int S = 4096;
static constexpr int B = 8;
static constexpr int D = 1024;
static constexpr int SB = S * B;
static constexpr long long NELEM = (long long)SB * D;
static constexpr int TP = 66;   // transpose tile row stride (bank-conflict-tuned)

__device__ __forceinline__ void load_lds16(const bf16* g, void* l)
{
    __builtin_amdgcn_global_load_lds(
        (const __attribute__((address_space(1))) void*)g,
        (__attribute__((address_space(3))) void*)l, 16, 0, 0);
}

// ---------------- 3x weight fp32 -> bf16 convert (merged) ----------------
__global__ void cvt_w3(const float* __restrict__ w0, const float* __restrict__ w1,
                       const float* __restrict__ w2, bf16* __restrict__ o0,
                       bf16* __restrict__ o1, bf16* __restrict__ o2)
{
    const float* in;
    bf16* out;
    if (blockIdx.y == 0)      { in = w0; out = o0; }
    else if (blockIdx.y == 1) { in = w1; out = o1; }
    else                      { in = w2; out = o2; }
    int i = (blockIdx.x * blockDim.x + threadIdx.x) * 4;
    float4 v = *(const float4*)(in + i);
    bf16x4 o;
    o[0] = (bf16)v.x; o[1] = (bf16)v.y; o[2] = (bf16)v.z; o[3] = (bf16)v.w;
    *(bf16x4*)(out + i) = o;
}

// ---- x [S][B][D] fp32 -> xbp [B][S][D] bf16 AND xT [B][D][S] bf16 (one pass) ----
__global__ __launch_bounds__(256) void cvt_permute_both(
    const float* __restrict__ in, bf16* __restrict__ xbp, bf16* __restrict__ xT)
{
    __shared__ bf16 tile[64 * TP];   // tile[f][s], stride TP=66
    const int b  = blockIdx.z;
    const int s0 = blockIdx.x * 64;
    const int f0 = blockIdx.y * 64;
    const int t  = threadIdx.x;
    const int rl = t >> 3;           // 0..31
    const int c8 = (t & 7) * 8;      // 0..56
    const long long SD = (long long)S * D;

    #pragma unroll
    for (int p = 0; p < 2; ++p) {
        const int r = rl + p * 32;   // s offset in tile
        const float* src = in + (long long)(s0 + r) * (B * D) + b * D + f0 + c8;
        float4 v0 = *(const float4*)(src);
        float4 v1 = *(const float4*)(src + 4);
        bf16x8 o;
        o[0] = (bf16)v0.x; o[1] = (bf16)v0.y; o[2] = (bf16)v0.z; o[3] = (bf16)v0.w;
        o[4] = (bf16)v1.x; o[5] = (bf16)v1.y; o[6] = (bf16)v1.z; o[7] = (bf16)v1.w;
        *(bf16x8*)(xbp + b * SD + (long long)(s0 + r) * D + f0 + c8) = o;
        #pragma unroll
        for (int j = 0; j < 8; ++j)
            tile[(c8 + j) * TP + r] = o[j];
    }
    __syncthreads();
    #pragma unroll
    for (int p = 0; p < 2; ++p) {
        const int fr = rl + p * 32;  // f offset in tile
        *(bf16x8*)(xT + b * SD + (long long)(f0 + fr) * S + s0 + c8) =
            *(const bf16x8*)(&tile[fr * TP + c8]);
    }
}

// ---------------- Wv (fp32 [e][d]) -> WvT (bf16 [d][e]) ----------------
__global__ __launch_bounds__(256) void cvt_transpose_1024(
    const float* __restrict__ in, bf16* __restrict__ out)
{
    __shared__ bf16 tile[64 * TP];   // tile[d][e], stride TP
    const int e0 = blockIdx.y * 64;
    const int d0 = blockIdx.x * 64;
    const int t  = threadIdx.x;
    const int rl = t >> 3;
    const int c8 = (t & 7) * 8;
    #pragma unroll
    for (int p = 0; p < 2; ++p) {
        int r = rl + p * 32;
        float4 v0 = *(const float4*)(in + (long long)(e0 + r) * D + d0 + c8);
        float4 v1 = *(const float4*)(in + (long long)(e0 + r) * D + d0 + c8 + 4);
        bf16x8 o;
        o[0] = (bf16)v0.x; o[1] = (bf16)v0.y; o[2] = (bf16)v0.z; o[3] = (bf16)v0.w;
        o[4] = (bf16)v1.x; o[5] = (bf16)v1.y; o[6] = (bf16)v1.z; o[7] = (bf16)v1.w;
        #pragma unroll
        for (int j = 0; j < 8; ++j)
            tile[(c8 + j) * TP + r] = o[j];
    }
    __syncthreads();
    #pragma unroll
    for (int p = 0; p < 2; ++p) {
        int dr = rl + p * 32;
        *(bf16x8*)(out + (long long)(d0 + dr) * D + e0 + c8) =
            *(const bf16x8*)(&tile[dr * TP + c8]);
    }
}

// ---------------- bvo = Wo @ bv (fp32) ----------------
__global__ __launch_bounds__(256) void bvo_kernel(
    const float* __restrict__ Wo, const float* __restrict__ bv, float* __restrict__ bvo)
{
    const int row = blockIdx.x;
    const int t = threadIdx.x;
    float4 w = *(const float4*)(Wo + (long long)row * D + t * 4);
    float4 b = *(const float4*)(bv + t * 4);
    float s = w.x*b.x + w.y*b.y + w.z*b.z + w.w*b.w;
    __shared__ float red[256];
    red[t] = s; __syncthreads();
    for (int off = 128; off > 0; off >>= 1) {
        if (t < off) red[t] += red[t + off];
        __syncthreads();
    }
    if (t == 0) bvo[row] = red[0];
}

// ---------------- MT[b] = part[2b] + part[2b+1], in-place into slab 2b ----------------
__global__ __launch_bounds__(256) void kv_add(bf16* __restrict__ p)
{
    const long long DD = (long long)D * D;
    const int b = blockIdx.y;
    const long long i = ((long long)blockIdx.x * 256 + threadIdx.x) * 8;
    bf16x8 u = *(const bf16x8*)(p + (2 * b) * DD + i);
    bf16x8 v = *(const bf16x8*)(p + (2 * b + 1) * DD + i);
    bf16x8 r;
    #pragma unroll
    for (int j = 0; j < 8; ++j) r[j] = (bf16)((float)u[j] + (float)v[j]);
    *(bf16x8*)(p + (2 * b) * DD + i) = r;   // same addr as u-read: race-free
}

// ---------------- R3 ring GEMM (small shapes: Wvo prep only) ----------------
template<int BM, int BN, int WM, int WN, int EPI, int OUTF32, int BIASROW>
__global__ __launch_bounds__(WM * WN * 64, 2) void gemm_bt(
    const bf16* __restrict__ A, const bf16* __restrict__ Bm,
    const float* __restrict__ bias, void* __restrict__ Cout,
    int lda, int ldb, int ldc, int K,
    long long aBatch, long long bBatch, long long cBatch)
{
    constexpr int THREADS = WM * WN * 64;
    constexpr int WROWS = BM / WM, WCOLS = BN / WN;
    constexpr int MI = WROWS / 16, NI = WCOLS / 16;
    constexpr int ABYTES = BM * 64;
    constexpr int BBYTES = BN * 64;
    constexpr int BUF = ABYTES + BBYTES;

    __shared__ unsigned char smem[4 * BUF];

    const int tid  = threadIdx.x;
    const int lane = tid & 63;
    const int wave = tid >> 6;
    const int wr   = wave / WN;
    const int wc   = wave % WN;
    const int bz   = blockIdx.z;

    const int nx  = gridDim.x;
    const int bid = blockIdx.y * nx + blockIdx.x;
    const int cpx = (nx * gridDim.y) >> 3;
    const int swz = (bid & 7) * cpx + (bid >> 3);
    const long long m0 = (long long)(swz / nx) * BM;
    const long long n0 = (long long)(swz % nx) * BN;

    const bf16* Ab = A  + bz * aBatch + m0 * lda;
    const bf16* Bb = Bm + bz * bBatch + n0 * ldb;

    f32x4 acc[MI][NI] = {};
    const int NT = K >> 5;

    auto stage = [&](int t) {
        unsigned char* dst = smem + (t & 3) * BUF;
        const long long kk = (long long)t << 5;
        #pragma unroll
        for (int j = 0; j < 2; ++j) {
            const int g  = wave * 64 + lane + j * THREADS;
            const int gs = g ^ ((g >> 3) & 3);
            const int row = gs >> 2, col = (gs & 3) * 8;
            load_lds16(Ab + (long long)row * lda + kk + col,
                       dst + (wave * 64 + j * THREADS) * 16);
        }
        #pragma unroll
        for (int j = 0; j < 2; ++j) {
            const int g  = wave * 64 + lane + j * THREADS;
            const int gs = g ^ ((g >> 3) & 3);
            const int row = gs >> 2, col = (gs & 3) * 8;
            load_lds16(Bb + (long long)row * ldb + kk + col,
                       dst + ABYTES + (wave * 64 + j * THREADS) * 16);
        }
    };

    stage(0); stage(1); stage(2);

    const int ko2 = (lane >> 4) * 16;
    const int la15 = lane & 15;

    for (int t = 0; t < NT; ++t) {
        if (t + 2 < NT)      asm volatile("s_waitcnt vmcnt(8)" ::: "memory");
        else if (t + 1 < NT) asm volatile("s_waitcnt vmcnt(4)" ::: "memory");
        else                 asm volatile("s_waitcnt vmcnt(0)" ::: "memory");
        __builtin_amdgcn_s_barrier();
        asm volatile("" ::: "memory");

        if (t + 3 < NT) stage(t + 3);

        const unsigned char* buf = smem + (t & 3) * BUF;
        bf16x8 a[MI], b[NI];
        #pragma unroll
        for (int mi = 0; mi < MI; ++mi) {
            int ad = (wr * WROWS + mi * 16 + la15) * 64 + ko2;
            ad ^= ((ad >> 7) & 3) << 4;
            a[mi] = *(const bf16x8*)(buf + ad);
        }
        #pragma unroll
        for (int ni = 0; ni < NI; ++ni) {
            int ad = (wc * WCOLS + ni * 16 + la15) * 64 + ko2;
            ad ^= ((ad >> 7) & 3) << 4;
            b[ni] = *(const bf16x8*)(buf + ABYTES + ad);
        }

        __builtin_amdgcn_s_setprio(1);
        #pragma unroll
        for (int mi = 0; mi < MI; ++mi)
            #pragma unroll
            for (int ni = 0; ni < NI; ++ni)
                acc[mi][ni] = __builtin_amdgcn_mfma_f32_16x16x32_bf16(
                    a[mi], b[ni], acc[mi][ni], 0, 0, 0);
        __builtin_amdgcn_s_setprio(0);
    }

    const int crow = (lane >> 4) * 4;
    const int ccol = lane & 15;
    #pragma unroll
    for (int ni = 0; ni < NI; ++ni) {
        const long long c = n0 + wc * WCOLS + ni * 16 + ccol;
        float bcol = 0.0f;
        if (!BIASROW && bias) bcol = bias[c];
        #pragma unroll
        for (int mi = 0; mi < MI; ++mi) {
            const long long r0 = m0 + wr * WROWS + mi * 16 + crow;
            #pragma unroll
            for (int j = 0; j < 4; ++j) {
                float v = acc[mi][ni][j];
                v += BIASROW ? bias[r0 + j] : bcol;
                if (EPI == 1) v = (v > 0.0f) ? (v + 1.0f) : __expf(v);
                const long long idx = bz * cBatch + (r0 + j) * ldc + c;
                if (OUTF32) ((float*)Cout)[idx] = v;
                else        ((bf16*)Cout)[idx]  = (bf16)v;
            }
        }
    }
}

// ---------------- 256^2 8-phase GEMM, single barrier/phase ----------------
// EPI: 1 = elu+1; 2 = elu+1 iff m0<1024; 3 = rank-1 add (v += bias[row]*ksum[col]);
//      4 = elu+1 AND atomic row-sum into ksum[batch*D + row] (K-projection).
// SPLITK: z = batch*SPLITK + kseg. GROUPN: 0 = A-reuse enum; 1 = B-reuse enum.
// Fence: sched_barrier(0x10F) = ALU|VALU|SALU|MFMA|DS_READ may cross (reads can
// hoist into prior MFMA shadow); VMEM + DS-writes pinned (stage-slot safety).
template<int EPI, int OUTF32, int BIASROW, int SPLITK, int GROUPN>
__global__ __launch_bounds__(512, 1) void gemm8p(
    const bf16* __restrict__ A, const bf16* __restrict__ Bm,
    const float* __restrict__ bias, float* __restrict__ ksum,
    void* __restrict__ Cout,
    int lda, int ldb, int ldc, int K,
    long long aBatch, long long bBatch, long long cBatch)
{
    __shared__ unsigned char smem[131072];

    const int tid  = threadIdx.x;
    const int lane = tid & 63;
    const int wave = tid >> 6;
    const int wr   = wave >> 2;
    const int wc   = wave & 3;
    const int bz    = blockIdx.z;
    const int batch = bz / SPLITK;
    const int kseg  = bz % SPLITK;

    const int nx  = gridDim.x;
    const int ny  = gridDim.y;
    const int bid = blockIdx.y * nx + blockIdx.x;
    const int cpx = (nx * ny) >> 3;
    const int swzb = (bid & 7) * cpx + (bid >> 3);
    long long m0, n0;
    if (GROUPN) { n0 = (long long)(swzb / ny) * 256; m0 = (long long)(swzb % ny) * 256; }
    else        { m0 = (long long)(swzb / nx) * 256; n0 = (long long)(swzb % nx) * 256; }

    const bf16* Ab = A  + batch * aBatch + m0 * lda + (long long)kseg * K;
    const bf16* Bb = Bm + batch * bBatch + n0 * ldb + (long long)kseg * K;

    const int sg = (lane & 3) ^ ((lane >> 3) & 3);
    const long long srow = wave * 32 + (lane >> 2);
    const bf16* srcA  = Ab + srow * lda + sg * 8;
    const bf16* srcA2 = srcA + 16 * (long long)lda;
    const bf16* srcB  = Bb + srow * ldb + sg * 8;
    const bf16* srcB2 = srcB + 16 * (long long)ldb;
    const int dstoff = wave * 2048;

    const int la15 = lane & 15;
    const int rsw  = (lane >> 4) ^ ((la15 >> 1) & 3);
    const int a16  = (wr * 128 + la15) * 4 + rsw;
    const int b16  = (wc * 64  + la15) * 4 + rsw;

    f32x4 acc[8][4] = {};
    const int NT = K >> 6;
    const int NI = NT >> 1;

    auto stageA = [&](int T, int kh) {
        const int reg = ((((T & 1) << 1) | kh) << 14);
        const long long kp = ((long long)T << 6) + (kh << 5);
        load_lds16(srcA  + kp, smem + reg + dstoff);
        load_lds16(srcA2 + kp, smem + reg + dstoff + 1024);
    };
    auto stageB = [&](int T, int kh) {
        const int reg = 65536 + ((((T & 1) << 1) | kh) << 14);
        const long long kp = ((long long)T << 6) + (kh << 5);
        load_lds16(srcB  + kp, smem + reg + dstoff);
        load_lds16(srcB2 + kp, smem + reg + dstoff + 1024);
    };

    stageB(0, 0); stageA(0, 0); stageB(0, 1); stageA(0, 1);
    stageB(1, 0); stageA(1, 0); stageB(1, 1);
    asm volatile("s_waitcnt vmcnt(6)" ::: "memory");

    bf16x8 bfr[4];
    for (int i = 0; i < NI; ++i) {
        const int t = 2 * i;
        const bool nl = (i + 1 < NI);
        #pragma unroll
        for (int p = 0; p < 8; ++p) {
            const int ks  = (p >> 1) & 1;
            const int ch  = p & 1;
            const int buf = p >> 2;
            const int regA = ((buf << 1) | ks) << 14;
            const int regB = 65536 + regA;

            __builtin_amdgcn_s_barrier();
            // permissive fence: DS_READ/ALU/MFMA may cross; VMEM & DS-write pinned
            __builtin_amdgcn_sched_barrier(0x10F);

            bf16x8 afr[4];
            if (ch == 0) {
                #pragma unroll
                for (int ni = 0; ni < 4; ++ni)
                    bfr[ni] = *(const bf16x8*)(smem + regB + (b16 + ni * 64) * 16);
            }
            #pragma unroll
            for (int m4 = 0; m4 < 4; ++m4)
                afr[m4] = *(const bf16x8*)(smem + regA + (a16 + (ch * 4 + m4) * 64) * 16);

            if      (p == 0) stageA(t + 1, 1);
            else if (p == 1) { if (t + 2 < NT) stageB(t + 2, 0); }
            else if (p == 2) { if (t + 2 < NT) stageA(t + 2, 0); }
            else if (p == 3) { if (t + 2 < NT) stageB(t + 2, 1); }
            else if (p == 4) { if (t + 2 < NT) stageA(t + 2, 1); }
            else if (p == 5) { if (t + 3 < NT) stageB(t + 3, 0); }
            else if (p == 6) { if (t + 3 < NT) stageA(t + 3, 0); }
            else             { if (t + 3 < NT) stageB(t + 3, 1); }

            if (p == 3) {
                if (nl) asm volatile("s_waitcnt vmcnt(6)" ::: "memory");
                else    asm volatile("s_waitcnt vmcnt(0)" ::: "memory");
            } else if (p == 7) {
                if (nl) asm volatile("s_waitcnt vmcnt(6)" ::: "memory");
            }

            __builtin_amdgcn_s_setprio(1);
            #pragma unroll
            for (int m4 = 0; m4 < 4; ++m4)
                #pragma unroll
                for (int ni = 0; ni < 4; ++ni)
                    acc[ch * 4 + m4][ni] = __builtin_amdgcn_mfma_f32_16x16x32_bf16(
                        afr[m4], bfr[ni], acc[ch * 4 + m4][ni], 0, 0, 0);
            __builtin_amdgcn_s_setprio(0);
        }
    }

    // ---- epilogue (all paths via LDS for contiguous stores) ----
    const bool doElu = (EPI == 1) || (EPI == 4) || (EPI == 2 && m0 < 1024);
    const long long cb = (long long)bz * cBatch;
    const int crow = (lane >> 4) * 4;

    if constexpr (OUTF32 != 0) {
        float* lt = (float*)smem;
        #pragma unroll
        for (int q = 0; q < 4; ++q) {
            __builtin_amdgcn_s_barrier();
            __builtin_amdgcn_sched_barrier(0);
            if (wr == (q >> 1)) {
                #pragma unroll
                for (int m4 = 0; m4 < 4; ++m4) {
                    const int mi = (q & 1) * 4 + m4;
                    const int lrow = m4 * 16 + crow;
                    const long long r0 = m0 + q * 64 + lrow;
                    #pragma unroll
                    for (int ni = 0; ni < 4; ++ni) {
                        const int lcol = wc * 64 + ni * 16 + la15;
                        float bb = 0.0f;
                        if (!BIASROW && bias) bb = bias[n0 + lcol];
                        #pragma unroll
                        for (int j = 0; j < 4; ++j) {
                            float v = acc[mi][ni][j] + (BIASROW ? bias[r0 + j] : bb);
                            if (doElu) v = (v > 0.0f) ? (v + 1.0f) : __expf(v);
                            lt[(lrow + j) * 260 + lcol] = v;
                        }
                    }
                }
            }
            __builtin_amdgcn_s_barrier();
            #pragma unroll
            for (int it = 0; it < 8; ++it) {
                const int chk = it * 512 + tid;
                const int r   = chk >> 6;
                const int g   = chk & 63;
                float4 v = *(const float4*)(lt + r * 260 + g * 4);
                *(float4*)((float*)Cout + cb + (m0 + q * 64 + r) * ldc + n0 + g * 4) = v;
            }
        }
    } else {
        bf16* lt = (bf16*)smem;
        #pragma unroll
        for (int half = 0; half < 2; ++half) {
            __builtin_amdgcn_s_barrier();
            __builtin_amdgcn_sched_barrier(0);
            if (wr == half) {
                #pragma unroll
                for (int mi = 0; mi < 8; ++mi) {
                    const int lrow = mi * 16 + crow;
                    const long long r0 = m0 + half * 128 + lrow;
                    #pragma unroll
                    for (int ni = 0; ni < 4; ++ni) {
                        const int lcol = wc * 64 + ni * 16 + la15;
                        float bb = 0.0f;
                        if (!BIASROW && bias) bb = bias[n0 + lcol];
                        float ksv = 0.0f;
                        if (EPI == 3 && ksum)
                            ksv = ksum[(long long)batch * D + n0 + lcol];
                        #pragma unroll
                        for (int j = 0; j < 4; ++j) {
                            float v;
                            if (EPI == 3) {
                                v = acc[mi][ni][j] + bias[r0 + j] * ksv;
                            } else {
                                v = acc[mi][ni][j] + (BIASROW ? bias[r0 + j] : bb);
                                if (doElu) v = (v > 0.0f) ? (v + 1.0f) : __expf(v);
                            }
                            lt[(lrow + j) * 264 + lcol] = (bf16)v;
                        }
                    }
                }
            }
            __builtin_amdgcn_s_barrier();
            #pragma unroll
            for (int it = 0; it < 8; ++it) {
                const int chk = it * 512 + tid;
                const int m   = chk >> 5;
                const int nof = (chk & 31) * 8;
                bf16x8 v = *(const bf16x8*)(lt + m * 264 + nof);
                *(bf16x8*)((bf16*)Cout + cb + (m0 + half * 128 + m) * ldc + n0 + nof) = v;
            }
            if constexpr (EPI == 4) {
                // Ksum: per-row (d) partial sums of this half-tile's 256 cols (s)
                const int row = tid >> 2;             // 0..127
                const bf16* rp = lt + row * 264 + (tid & 3) * 64;
                float s = 0.0f;
                #pragma unroll
                for (int e8 = 0; e8 < 8; ++e8) {
                    bf16x8 v = *(const bf16x8*)(rp + e8 * 8);
                    #pragma unroll
                    for (int j = 0; j < 8; ++j) s += (float)v[j];
                }
                s += __shfl_down(s, 2);
                s += __shfl_down(s, 1);
                if ((tid & 3) == 0)
                    atomicAdd(ksum + (long long)batch * D + m0 + half * 128 + row, s);
            }
        }
    }
}

// ---------------- launch ----------------
extern "C" void kernel_launch(void* const* d_in, const int* in_sizes, int n_in,
                              void* d_out, int out_size, void* d_ws, size_t ws_size,
                              hipStream_t stream)
{
    const float* x  = (const float*)d_in[0];
    const float* Wq = (const float*)d_in[1];
    const float* bq = (const float*)d_in[2];
    const float* Wk = (const float*)d_in[3];
    const float* bk = (const float*)d_in[4];
    const float* Wv = (const float*)d_in[5];
    const float* bv = (const float*)d_in[6];
    const float* Wo = (const float*)d_in[7];
    const float* bo = (const float*)d_in[8];
    float* out = (float*)d_out;

    // ws layout (152 MiB):
    //  [0,64M)     xbp [b][s][f]
    //  [64M,96M)   M partials (16 x 2MB slabs) -> MT in even slabs -> then Qb
    //  [96M,96M+32K)  Ksum (fp32 8192)   [+32K,+36K) bvo  (both die before Qb)
    //  [64M,128M)  Qb (written after KVo-gemm; clobbers partials/Ksum/bvo)
    //  [128M,144M) wvT temp (2MB, dead early) -> then KVo (16MB)
    //  [144M,152M) wqb | wob | wkb | Wvo  (2MB each)
    // d_out scratch: Kt [0,64M), xT [64M,128M) — both dead before final write.
    char* ws = (char*)d_ws;
    if (ws_size < (size_t)159383552) return;
    bf16*  xbp  = (bf16*)(ws + 0);
    bf16*  part = (bf16*)(ws + 67108864);
    bf16*  Qb   = (bf16*)(ws + 67108864);
    float* ks   = (float*)(ws + 100663296);
    float* bvo  = (float*)(ws + 100663296 + 32768);
    bf16*  wvT  = (bf16*)(ws + 134217728);
    bf16*  KVo  = (bf16*)(ws + 134217728);
    bf16*  wqb  = (bf16*)(ws + 150994944);
    bf16*  wob  = wqb + 1048576;
    bf16*  wkb  = wob + 1048576;
    bf16*  Wvo  = wkb + 1048576;
    bf16*  Kt   = (bf16*)d_out;            // [b][d][s]
    bf16*  xT   = Kt + NELEM;              // [b][f][s]

    const long long SD = (long long)S * D;
    const long long DD = (long long)D * D;

    // 1) converts + folded-weight prep (x permute + transpose fused, one pass)
    cvt_permute_both<<<dim3(64, 16, 8), 256, 0, stream>>>(x, xbp, xT);
    cvt_w3<<<dim3(1024, 3), 256, 0, stream>>>(Wq, Wo, Wk, wqb, wob, wkb);
    cvt_transpose_1024<<<dim3(16, 16), 256, 0, stream>>>(Wv, wvT);
    bvo_kernel<<<1024, 256, 0, stream>>>(Wo, bv, bvo);
    hipMemsetAsync(ks, 0, B * D * sizeof(float), stream);

    // 2) Wvo[e'][f] = sum_ve Wo[e'][ve] Wv[ve][f]  (A=wob, B=wvT)
    gemm_bt<128, 128, 2, 2, 0, 0, 0><<<dim3(8, 8, 1), 256, 0, stream>>>(
        wob, wvT, nullptr, Wvo, D, D, D, D, 0, 0, 0);

    // 3) K projection + fused Ksum: Kt[b][d][s] = elu(Wk xbp_b^T + bk)+1,
    //    ks[b][d] += row sums (atomic, 16 tiles contribute per row)
    gemm8p<4, 0, 1, 1, 1><<<dim3(16, 4, 8), 512, 0, stream>>>(
        wkb, xbp, bk, ks, Kt, D, D, S, D, 0, SD, SD);

    // 4) M partials: part[2b+h][d][f] = sum_{s half h} Kt[b][d][s] xT[b][f][s]
    gemm8p<0, 0, 0, 2, 0><<<dim3(4, 4, 16), 512, 0, stream>>>(
        Kt, xT, nullptr, nullptr, part, S, S, D, 2048, SD, SD, DD);

    // 5) MT[b] = part[2b] + part[2b+1]  (in-place into even slabs)
    kv_add<<<dim3(512, 8), 256, 0, stream>>>(part);

    // 6) KVo[b][e'][d] = sum_f Wvo[e'][f] MT[b][d][f] + bvo[e']*Ksum[b][d]
    gemm8p<3, 0, 1, 1, 0><<<dim3(4, 4, 8), 512, 0, stream>>>(
        Wvo, part, bvo, ks, KVo, D, D, D, D, 0, 2 * DD, DD);

    // 7) Qb[b][s][d] = elu(xbp_b Wq^T + bq)+1  (clobbers partials/Ksum/bvo)
    gemm8p<1, 0, 0, 1, 0><<<dim3(4, 16, 8), 512, 0, stream>>>(
        xbp, wqb, bq, nullptr, Qb, D, D, D, D, SD, 0, SD);

    // 8) out[s][b][e'] = Qb[b] @ KVo[b]^T + bo  (fp32; C row s at b*D offset)
    gemm8p<0, 1, 0, 1, 0><<<dim3(4, 16, 8), 512, 0, stream>>>(
        Qb, KVo, bo, nullptr, out, D, D, B * D, D,
        SD, DD, (long long)D);
}